// Round 5
// baseline (331.053 us; speedup 1.0000x reference)
//
#include <hip/hip_runtime.h>
#include <math.h>

#define S_LEN 2048
#define DMODEL 1024
#define NHEADS 16
#define HDIM 64
#define QPITCH 1280   // q|ckv merged activation pitch

typedef __bf16 bf16x8 __attribute__((ext_vector_type(8)));
typedef __bf16 bf16x4 __attribute__((ext_vector_type(4)));
typedef float  f32x4  __attribute__((ext_vector_type(4)));

// async global->LDS, 16B per lane. LDS dest = wave-uniform base + lane*16.
__device__ __forceinline__ void gld_lds16(void* lds, const void* g) {
    __builtin_amdgcn_global_load_lds(
        (__attribute__((address_space(1))) void*)(g),
        (__attribute__((address_space(3))) void*)(lds), 16, 0, 0);
}

// ---------------------------------------------------------------------------
// bf16 MFMA GEMM, double-buffered one-barrier pipeline.
// C[M,N] = A[M,K] @ Bt[N,K]^T. 128x128 tile, BK=64, 256 thr = 4 waves.
// grid.z = ksplit: each z-slice does K/gridDim.z; Cf written via atomicAdd
// when nz>1 (Cf must be pre-zeroed; bias applied on z==0 only; Cb null).
// bf16 modes: 0 plain [m][n]; 3 B-split hi|hi|lo; 4 dual (n<1024 row-major,
// n>=1024 transposed into Cb2).
// ---------------------------------------------------------------------------
__global__ __launch_bounds__(256) void gemm_bf16(
    const __bf16* __restrict__ A, int lda,
    const __bf16* __restrict__ Bt, int ldb,
    int M, int N, int K,
    float* __restrict__ Cf, int ldcf, const float* __restrict__ bias,
    __bf16* __restrict__ Cb, int ldcb, int bmode, int soff,
    __bf16* __restrict__ Cb2, int ldcb2, float out_scale)
{
    __shared__ __bf16 sA[2][128 * 64];
    __shared__ __bf16 sB[2][128 * 64];

    const int tid  = threadIdx.x;
    const int lane = tid & 63;
    const int w    = tid >> 6;
    const int quad = lane >> 4;
    const int c0   = lane & 15;
    const int m0 = blockIdx.y * 128;
    const int n0 = blockIdx.x * 128;

    const int nkt_tot = K >> 6;
    const int nz  = gridDim.z;
    const int nkt = nkt_tot / nz;
    const int kt0 = blockIdx.z * nkt;

    const int srow = lane >> 3;
    const int sc   = lane & 7;
    const __bf16* a_src[4]; const __bf16* b_src[4];
    int dstoff[4];
#pragma unroll
    for (int t = 0; t < 4; t++) {
        const int row = w * 32 + t * 8 + srow;
        const int c = sc ^ (row & 7);
        a_src[t] = A  + (size_t)(m0 + row) * lda + kt0 * 64 + c * 8;
        b_src[t] = Bt + (size_t)(n0 + row) * ldb + kt0 * 64 + c * 8;
        dstoff[t] = (w * 32 + t * 8) * 64;
    }

    const int mw = (w & 1) * 64;
    const int nw = (w >> 1) * 64;
    int arow[4], brow[4];
#pragma unroll
    for (int i = 0; i < 4; i++) {
        arow[i] = mw + i * 16 + c0;
        brow[i] = nw + i * 16 + c0;
    }

    f32x4 acc[4][4];
#pragma unroll
    for (int i = 0; i < 4; i++)
#pragma unroll
        for (int j = 0; j < 4; j++) acc[i][j] = (f32x4){0.f, 0.f, 0.f, 0.f};

#pragma unroll
    for (int t = 0; t < 4; t++) {
        gld_lds16(&sA[0][dstoff[t]], a_src[t]); a_src[t] += 64;
        gld_lds16(&sB[0][dstoff[t]], b_src[t]); b_src[t] += 64;
    }

    for (int kt = 0; kt < nkt; kt++) {
        __syncthreads();
        const int cur = kt & 1;
        if (kt + 1 < nkt) {
#pragma unroll
            for (int t = 0; t < 4; t++) {
                gld_lds16(&sA[cur ^ 1][dstoff[t]], a_src[t]); a_src[t] += 64;
                gld_lds16(&sB[cur ^ 1][dstoff[t]], b_src[t]); b_src[t] += 64;
            }
        }
#pragma unroll
        for (int ks = 0; ks < 2; ks++) {
            const int cb = ks * 4 + quad;
            bf16x8 af[4], bf[4];
#pragma unroll
            for (int i = 0; i < 4; i++)
                af[i] = *(const bf16x8*)&sA[cur][arow[i] * 64 + ((cb ^ (arow[i] & 7)) << 3)];
#pragma unroll
            for (int j = 0; j < 4; j++)
                bf[j] = *(const bf16x8*)&sB[cur][brow[j] * 64 + ((cb ^ (brow[j] & 7)) << 3)];
#pragma unroll
            for (int i = 0; i < 4; i++)
#pragma unroll
                for (int j = 0; j < 4; j++)
                    acc[i][j] = __builtin_amdgcn_mfma_f32_16x16x32_bf16(af[i], bf[j], acc[i][j], 0, 0, 0);
        }
    }

    float bias_v[4];
    if (bias) {
#pragma unroll
        for (int j = 0; j < 4; j++) bias_v[j] = bias[n0 + nw + j * 16 + c0];
    }
    const bool addb = bias && (blockIdx.z == 0);
#pragma unroll
    for (int i = 0; i < 4; i++) {
#pragma unroll
        for (int reg = 0; reg < 4; reg++) {
            const int m = m0 + mw + i * 16 + quad * 4 + reg;
#pragma unroll
            for (int j = 0; j < 4; j++) {
                const int n = n0 + nw + j * 16 + c0;
                float val = acc[i][j][reg] * out_scale;
                if (addb) val += bias_v[j];
                if (Cf) {
                    if (nz > 1) atomicAdd(&Cf[(size_t)m * ldcf + n], val);
                    else        Cf[(size_t)m * ldcf + n] = val;
                }
                if (Cb) {
                    if (bmode == 0) {
                        Cb[(size_t)m * ldcb + n] = (__bf16)val;
                    } else if (bmode == 3) {
                        __bf16 hi = (__bf16)val;
                        __bf16 lo = (__bf16)(val - (float)hi);
                        __bf16* p = Cb + (size_t)m * ldcb + n;
                        p[0] = hi; p[soff] = hi; p[2 * soff] = lo;
                    } else { // 4: dual k | vT
                        __bf16 hv = (__bf16)val;
                        if (n < 1024) Cb[(size_t)m * ldcb + n] = hv;
                        else          Cb2[(size_t)(n - 1024) * ldcb2 + m] = hv;
                    }
                }
            }
        }
    }
}

// ---------------------------------------------------------------------------
// MFMA flash attention, fixed-max softmax, NO K/V LDS staging: K and V
// fragments loaded straight from global (both k-contiguous in B-operand
// layout; L1 catches the 4-wave intra-block reuse: 16KB/tile <= 32KB L1).
// Zero __syncthreads in the K-loop (P strip is wave-local LDS).
// qs bf16 [S,QPITCH] (q pre-scaled, cols 0-1023); kk bf16 [S,1024];
// vT bf16 [1024,S]. Output ctx2 bf16 [S,3072] hi|lo|hi.
// ---------------------------------------------------------------------------
#define PITCH 72
#define SOFT_M0 16.0f

__global__ __launch_bounds__(256) void attn_mfma_kernel(
    const __bf16* __restrict__ qs,
    const __bf16* __restrict__ kk,
    const __bf16* __restrict__ vT,
    __bf16* __restrict__ ctx2)
{
    __shared__ __bf16 Ps[4 * 16 * PITCH];

    const int bid = blockIdx.x;
    const int h  = bid & 15;      // bid%8 pins a head's blocks to one XCD
    const int qb = bid >> 4;
    const int tid  = threadIdx.x;
    const int lane = tid & 63;
    const int w    = tid >> 6;
    const int quad = lane >> 4;
    const int c0   = lane & 15;

    bf16x8 qfrag[2];
    {
        const __bf16* qrow = qs + (size_t)(qb * 64 + w * 16 + c0) * QPITCH + h * HDIM;
        qfrag[0] = *(const bf16x8*)(qrow + quad * 8);
        qfrag[1] = *(const bf16x8*)(qrow + 32 + quad * 8);
    }

    // lane-fixed fragment bases (B-operand: n = c0, k-chunk = ks*32 + quad*8)
    const __bf16* kbase = kk + (size_t)c0 * DMODEL + h * HDIM + quad * 8;
    const __bf16* vbase = vT + (size_t)(h * HDIM + c0) * S_LEN + quad * 8;

    f32x4 Ofrag[4];
#pragma unroll
    for (int nb = 0; nb < 4; nb++) Ofrag[nb] = (f32x4){0.f, 0.f, 0.f, 0.f};
    float l_r[4] = {0.f, 0.f, 0.f, 0.f};

    __bf16* Pw = Ps + w * (16 * PITCH);

    for (int kt = 0; kt < S_LEN / 64; kt++) {
        // K fragments (8 x 16B loads, all independent)
        bf16x8 kf[4][2];
#pragma unroll
        for (int nb = 0; nb < 4; nb++)
#pragma unroll
            for (int ks = 0; ks < 2; ks++)
                kf[nb][ks] = *(const bf16x8*)(kbase + (size_t)(kt * 64 + nb * 16) * DMODEL + ks * 32);

        // V fragments issued early (independent of softmax)
        bf16x8 vf[4][2];
#pragma unroll
        for (int nb = 0; nb < 4; nb++)
#pragma unroll
            for (int ks = 0; ks < 2; ks++)
                vf[nb][ks] = *(const bf16x8*)(vbase + (size_t)(nb * 16) * S_LEN + kt * 64 + ks * 32);

        // scores
        f32x4 sfrag[4];
#pragma unroll
        for (int nb = 0; nb < 4; nb++) {
            f32x4 acc = (f32x4){0.f, 0.f, 0.f, 0.f};
#pragma unroll
            for (int ks = 0; ks < 2; ks++)
                acc = __builtin_amdgcn_mfma_f32_16x16x32_bf16(qfrag[ks], kf[nb][ks], acc, 0, 0, 0);
            sfrag[nb] = acc;
        }

        // P = exp(s - M0); per-lane partial row sums (no shuffles in loop)
#pragma unroll
        for (int reg = 0; reg < 4; reg++) {
            float p0 = __expf(sfrag[0][reg] - SOFT_M0);
            float p1 = __expf(sfrag[1][reg] - SOFT_M0);
            float p2 = __expf(sfrag[2][reg] - SOFT_M0);
            float p3 = __expf(sfrag[3][reg] - SOFT_M0);
            sfrag[0][reg] = p0; sfrag[1][reg] = p1;
            sfrag[2][reg] = p2; sfrag[3][reg] = p3;
            l_r[reg] += p0 + p1 + p2 + p3;
        }

        // P: C-layout -> wave-local LDS strip -> A-layout
#pragma unroll
        for (int reg = 0; reg < 4; reg++) {
            const int prow = quad * 4 + reg;
#pragma unroll
            for (int nb = 0; nb < 4; nb++)
                Pw[prow * PITCH + nb * 16 + c0] = (__bf16)sfrag[nb][reg];
        }
        __asm__ __volatile__("s_waitcnt lgkmcnt(0)" ::: "memory");

        bf16x8 pfrag[2];
#pragma unroll
        for (int ks = 0; ks < 2; ks++)
            pfrag[ks] = *(const bf16x8*)&Pw[c0 * PITCH + ks * 32 + quad * 8];

        // O += P @ V
#pragma unroll
        for (int nb = 0; nb < 4; nb++) {
            f32x4 acc = Ofrag[nb];
#pragma unroll
            for (int ks = 0; ks < 2; ks++)
                acc = __builtin_amdgcn_mfma_f32_16x16x32_bf16(pfrag[ks], vf[nb][ks], acc, 0, 0, 0);
            Ofrag[nb] = acc;
        }
    }

    float inv_l[4];
#pragma unroll
    for (int reg = 0; reg < 4; reg++) {
        float rsum = l_r[reg];
#pragma unroll
        for (int mask = 1; mask < 16; mask <<= 1)
            rsum += __shfl_xor(rsum, mask, 64);
        inv_l[reg] = 1.0f / rsum;
    }

#pragma unroll
    for (int reg = 0; reg < 4; reg++) {
        const int row = qb * 64 + w * 16 + quad * 4 + reg;
#pragma unroll
        for (int nb = 0; nb < 4; nb++) {
            const int col = h * HDIM + nb * 16 + c0;
            float val = Ofrag[nb][reg] * inv_l[reg];
            __bf16 hi = (__bf16)val;
            __bf16 lo = (__bf16)(val - (float)hi);
            __bf16* p = ctx2 + (size_t)row * 3072 + col;
            p[0] = hi; p[1024] = lo; p[2048] = hi;
        }
    }
}

// ---------------------------------------------------------------------------
// Prep building blocks (device functions shared by megaprep + standalone)
// ---------------------------------------------------------------------------
__device__ __forceinline__ void xpose_seg(float (*tile)[33],
    const float* __restrict__ src, __bf16* __restrict__ dst,
    int R, int C, int dpitch, int split, float scale, int bx, int by, int nbase0)
{
    const int r0 = by * 32, c0 = bx * 32;
    const int tr = threadIdx.x >> 5, tc = threadIdx.x & 31;
#pragma unroll
    for (int i = 0; i < 4; i++)
        tile[tr + i * 8][tc] = src[(size_t)(r0 + tr + i * 8) * C + c0 + tc];
    __syncthreads();
#pragma unroll
    for (int i = 0; i < 4; i++) {
        const int n = nbase0 + c0 + tr + i * 8;
        const int kk = r0 + tc;
        const float v = tile[tc][tr + i * 8] * scale;
        __bf16 hi = (__bf16)v;
        __bf16* dp = dst + (size_t)n * dpitch + kk;
        dp[0] = hi;
        if (split == 1)      { dp[R] = hi; dp[2 * R] = (__bf16)(v - (float)hi); }
        else if (split == 2) { dp[R] = (__bf16)(v - (float)hi); dp[2 * R] = hi; }
    }
}

// fp32 [rows][1024] -> bf16 [rows][3072] B-split (hi|hi|lo); idx over float4s
__device__ __forceinline__ void bsplit_seg(
    const float* __restrict__ src, __bf16* __restrict__ dst, int idx)
{
    const int row = idx >> 8;
    const int c4  = (idx & 255) * 4;
    float4 f = ((const float4*)src)[idx];
    __bf16* p = dst + (size_t)row * 3072 + c4;
    float fa[4] = {f.x, f.y, f.z, f.w};
#pragma unroll
    for (int e = 0; e < 4; e++) {
        __bf16 hi = (__bf16)fa[e];
        p[e] = hi; p[1024 + e] = hi; p[2048 + e] = (__bf16)(fa[e] - (float)hi);
    }
}

__global__ __launch_bounds__(256) void convert_bsplit_kernel(
    const float* __restrict__ src, __bf16* __restrict__ dst, int n4)
{
    const int i = blockIdx.x * blockDim.x + threadIdx.x;
    if (i < n4) bsplit_seg(src, dst, i);
}

// ---------------------------------------------------------------------------
// megaprep: all weight transposes/converts + emb convert + zeros + bias,
// one launch, block-range ladder. 12040 blocks total.
// ---------------------------------------------------------------------------
__global__ __launch_bounds__(256) void megaprep_kernel(
    const float* __restrict__ emb, const float* __restrict__ Wq,
    const float* __restrict__ Wdkv, const float* __restrict__ Wuk,
    const float* __restrict__ Wuv, const float* __restrict__ Wo,
    const float* __restrict__ wheelW, const float* __restrict__ wheelB,
    __bf16* __restrict__ Wqc_t, __bf16* __restrict__ Wukv_t,
    __bf16* __restrict__ Bt_full, __bf16* __restrict__ WcT2a,
    __bf16* __restrict__ Wo_rm, __bf16* __restrict__ emb_bf,
    float* __restrict__ out_zero, float* __restrict__ Wf_acc,
    float* __restrict__ biasbuf)
{
    __shared__ float tile[32][33];
    int b = blockIdx.x;
    const int tid = threadIdx.x;

    if (b < 1024) { xpose_seg(tile, Wq, Wqc_t, 1024, 1024, 1024, 0, 0.125f, b & 31, b >> 5, 0); return; }
    b -= 1024;
    if (b < 256)  { xpose_seg(tile, Wdkv, Wqc_t + 1048576, 1024, 256, 1024, 0, 1.f, b & 7, b >> 3, 0); return; }
    b -= 256;
    if (b < 256)  { xpose_seg(tile, Wuk, Wukv_t, 256, 1024, 256, 0, 1.f, b & 31, b >> 5, 0); return; }
    b -= 256;
    if (b < 256)  { xpose_seg(tile, Wuv, Wukv_t + 262144, 256, 1024, 256, 0, 1.f, b & 31, b >> 5, 0); return; }
    b -= 256;
    if (b < 1024) { xpose_seg(tile, Wo, Bt_full, 1024, 1024, 3072, 1, 1.f, b & 31, b >> 5, 0); return; }
    b -= 1024;
    if (b < 1024) {  // wheelW batch of 4 -> WcT2a A-split
        const int z = b >> 8, rem = b & 255;
        xpose_seg(tile, wheelW + (size_t)z * 262144, WcT2a, 1024, 256, 3072, 2, 1.f,
                  rem & 7, rem >> 3, z * 256);
        return;
    }
    b -= 1024;
    if (b < 1024) { bsplit_seg(Wo, Wo_rm, b * 256 + tid); return; }   // n4=262144
    b -= 1024;
    if (b < 2048) {  // emb fp32 -> bf16 (n4=524288)
        const int i = b * 256 + tid;
        float4 f = ((const float4*)emb)[i];
        bf16x4 v;
        v[0] = (__bf16)f.x; v[1] = (__bf16)f.y; v[2] = (__bf16)f.z; v[3] = (__bf16)f.w;
        ((bf16x4*)emb_bf)[i] = v;
        return;
    }
    b -= 2048;
    if (b < 4096) {  // zero out (2048x2048 fp32, n4=1048576)
        ((float4*)out_zero)[b * 256 + tid] = make_float4(0.f, 0.f, 0.f, 0.f);
        return;
    }
    b -= 4096;
    if (b < 1024) {  // zero Wf_acc (n4=262144)
        ((float4*)Wf_acc)[b * 256 + tid] = make_float4(0.f, 0.f, 0.f, 0.f);
        return;
    }
    b -= 1024;
    if (b < 8) {     // bias: [0:1024]=0, [1024:2048]=wheelB flat
        const int i = b * 256 + tid;
        biasbuf[i] = (i < 1024) ? 0.f : wheelB[i - 1024];
    }
}

// ---------------------------------------------------------------------------
// Launch
// ---------------------------------------------------------------------------
extern "C" void kernel_launch(void* const* d_in, const int* in_sizes, int n_in,
                              void* d_out, int out_size, void* d_ws, size_t ws_size,
                              hipStream_t stream) {
    const float* emb    = (const float*)d_in[0];
    const float* Wq     = (const float*)d_in[1];
    const float* Wdkv   = (const float*)d_in[2];
    const float* Wuk    = (const float*)d_in[3];
    const float* Wuv    = (const float*)d_in[4];
    const float* Wo     = (const float*)d_in[5];
    const float* wheelW = (const float*)d_in[6];
    const float* wheelB = (const float*)d_in[7];
    float* out = (float*)d_out;

    // workspace layout (bf16 element offsets); high-water ~42.5 MB
    __bf16* ws = (__bf16*)d_ws;
    __bf16* Bt_full = ws;                        // [2048][3072]
    __bf16* Wqc_t   = ws + 6291456;              // [1280][1024]
    __bf16* Wukv_t  = ws + 7602176;              // [2048][256]
    float*  biasbuf = (float*)(ws + 8126464);    // fp32[2048]
    __bf16* WcT2a   = ws + 8130560;              // [1024][3072] A-split
    __bf16* Wo_rm   = ws + 11276288;             // [1024][3072] B-split
    __bf16* emb_bf  = ws + 8130560 + 6291456 - 2097152;  // tail of E region
    __bf16* ctx2    = ws + 8130560;              // [2048][3072] (attn out)
    float*  Wf_acc  = (float*)(ws + 14422016);   // fp32[1024][1024] (aliases qc_bf)
    __bf16* qc_bf   = ws + 14422016;             // [2048][1280]
    __bf16* k_bf    = ws + 17043456;             // [2048][1024]
    __bf16* vT_bf   = ws + 19140608;             // [1024][2048]

    // NOTE: emb_bf must not collide with WcT2a/Wo_rm (all live until qckv GEMM
    // and Wf GEMM respectively). E region is 6291456 elems: WcT2a(3145728) +
    // Wo_rm(3145728) fill it. Put emb_bf AFTER vT instead:
    emb_bf = ws + 21237760;                      // [2048][1024]

    // 1) megaprep (everything parallel, one launch)
    megaprep_kernel<<<12040, 256, 0, stream>>>(
        emb, Wq, Wdkv, Wuk, Wuv, Wo, wheelW, wheelB,
        Wqc_t, Wukv_t, Bt_full, WcT2a, Wo_rm, emb_bf, out, Wf_acc, biasbuf);

    // 2) Wf = Wo @ Wc (fp32-exact via split operands), split-K x8 -> 512 blocks
    gemm_bf16<<<dim3(8, 8, 8), 256, 0, stream>>>(WcT2a, 3072, Wo_rm, 3072, 1024, 1024, 3072,
        Wf_acc, 1024, nullptr, nullptr, 0, 0, 0, nullptr, 0, 1.0f);

    // 3) Wf -> Bt_full rows 1024..2047 (B-split)
    convert_bsplit_kernel<<<1024, 256, 0, stream>>>(Wf_acc, Bt_full + (size_t)1024 * 3072, 262144);

    // 4) q|ckv merged
    gemm_bf16<<<dim3(10, 16, 1), 256, 0, stream>>>(emb_bf, 1024, Wqc_t, 1024, S_LEN, 1280, 1024,
        nullptr, 0, nullptr, qc_bf, 1280, 0, 0, nullptr, 0, 1.0f);

    // 5) k|vT merged (A = ckv cols of qc_bf)
    gemm_bf16<<<dim3(16, 16, 1), 256, 0, stream>>>(qc_bf + 1024, 1280, Wukv_t, 256, S_LEN, 2048, 256,
        nullptr, 0, nullptr, k_bf, 1024, 4, 0, vT_bf, 2048, 1.0f);

    // 6) attention -> ctx2 (hi|lo|hi)
    attn_mfma_kernel<<<512, 256, 0, stream>>>(qc_bf, k_bf, vT_bf, ctx2);

    // 7) final fused GEMM, split-K x2 -> 512 blocks, atomic into zeroed out
    gemm_bf16<<<dim3(16, 16, 2), 256, 0, stream>>>(ctx2, 3072, Bt_full, 3072, S_LEN, 2048, 3072,
        out, 2048, biasbuf, nullptr, 0, 0, 0, nullptr, 0, 1.0f);
}

// Round 6
// 249.162 us; speedup vs baseline: 1.3287x; 1.3287x over previous
//
#include <hip/hip_runtime.h>
#include <math.h>

#define S_LEN 2048
#define DMODEL 1024
#define NHEADS 16
#define HDIM 64
#define QPITCH 1280   // q|ckv merged activation pitch

typedef __bf16 bf16x8 __attribute__((ext_vector_type(8)));
typedef __bf16 bf16x4 __attribute__((ext_vector_type(4)));
typedef float  f32x4  __attribute__((ext_vector_type(4)));

// async global->LDS, 16B per lane. LDS dest = wave-uniform base + lane*16.
__device__ __forceinline__ void gld_lds16(void* lds, const void* g) {
    __builtin_amdgcn_global_load_lds(
        (__attribute__((address_space(1))) void*)(g),
        (__attribute__((address_space(3))) void*)(lds), 16, 0, 0);
}

// ---------------------------------------------------------------------------
// bf16 MFMA GEMM core (device fn), double-buffered one-barrier pipeline.
// C[M,N] = A[M,K] @ Bt[N,K]^T. 128x128 tile, BK=64, 256 thr = 4 waves.
// nz>1: z-slice of K with atomicAdd into pre-zeroed Cf.
// bf16 modes: 0 plain [m][n]; 4 dual (n<1024 row-major k_bf, n>=1024
// transposed into Cb2).
// ---------------------------------------------------------------------------
__device__ __forceinline__ void gemm_core(
    __bf16* sA, __bf16* sB,                       // each [2][128*64]
    const __bf16* __restrict__ A, int lda,
    const __bf16* __restrict__ Bt, int ldb, int K,
    float* __restrict__ Cf, int ldcf,
    __bf16* __restrict__ Cb, int ldcb, int bmode,
    __bf16* __restrict__ Cb2, int ldcb2,
    int bx, int by, int bz, int nz)
{
    const int tid  = threadIdx.x;
    const int lane = tid & 63;
    const int w    = tid >> 6;
    const int quad = lane >> 4;
    const int c0   = lane & 15;
    const int m0 = by * 128;
    const int n0 = bx * 128;

    const int nkt = (K >> 6) / nz;
    const int kt0 = bz * nkt;

    const int srow = lane >> 3;
    const int sc   = lane & 7;
    const __bf16* a_src[4]; const __bf16* b_src[4];
    int dstoff[4];
#pragma unroll
    for (int t = 0; t < 4; t++) {
        const int row = w * 32 + t * 8 + srow;
        const int c = sc ^ (row & 7);
        a_src[t] = A  + (size_t)(m0 + row) * lda + kt0 * 64 + c * 8;
        b_src[t] = Bt + (size_t)(n0 + row) * ldb + kt0 * 64 + c * 8;
        dstoff[t] = (w * 32 + t * 8) * 64;
    }

    const int mw = (w & 1) * 64;
    const int nw = (w >> 1) * 64;
    int arow[4], brow[4];
#pragma unroll
    for (int i = 0; i < 4; i++) {
        arow[i] = mw + i * 16 + c0;
        brow[i] = nw + i * 16 + c0;
    }

    f32x4 acc[4][4];
#pragma unroll
    for (int i = 0; i < 4; i++)
#pragma unroll
        for (int j = 0; j < 4; j++) acc[i][j] = (f32x4){0.f, 0.f, 0.f, 0.f};

#pragma unroll
    for (int t = 0; t < 4; t++) {
        gld_lds16(&sA[dstoff[t]], a_src[t]); a_src[t] += 64;
        gld_lds16(&sB[dstoff[t]], b_src[t]); b_src[t] += 64;
    }

    for (int kt = 0; kt < nkt; kt++) {
        __syncthreads();
        const int cur = kt & 1;
        if (kt + 1 < nkt) {
#pragma unroll
            for (int t = 0; t < 4; t++) {
                gld_lds16(&sA[(cur ^ 1) * 8192 + dstoff[t]], a_src[t]); a_src[t] += 64;
                gld_lds16(&sB[(cur ^ 1) * 8192 + dstoff[t]], b_src[t]); b_src[t] += 64;
            }
        }
#pragma unroll
        for (int ks = 0; ks < 2; ks++) {
            const int cb = ks * 4 + quad;
            bf16x8 af[4], bf[4];
#pragma unroll
            for (int i = 0; i < 4; i++)
                af[i] = *(const bf16x8*)&sA[cur * 8192 + arow[i] * 64 + ((cb ^ (arow[i] & 7)) << 3)];
#pragma unroll
            for (int j = 0; j < 4; j++)
                bf[j] = *(const bf16x8*)&sB[cur * 8192 + brow[j] * 64 + ((cb ^ (brow[j] & 7)) << 3)];
#pragma unroll
            for (int i = 0; i < 4; i++)
#pragma unroll
                for (int j = 0; j < 4; j++)
                    acc[i][j] = __builtin_amdgcn_mfma_f32_16x16x32_bf16(af[i], bf[j], acc[i][j], 0, 0, 0);
        }
    }

#pragma unroll
    for (int i = 0; i < 4; i++) {
#pragma unroll
        for (int reg = 0; reg < 4; reg++) {
            const int m = m0 + mw + i * 16 + quad * 4 + reg;
#pragma unroll
            for (int j = 0; j < 4; j++) {
                const int n = n0 + nw + j * 16 + c0;
                float val = acc[i][j][reg];
                if (Cf) {
                    if (nz > 1) atomicAdd(&Cf[(size_t)m * ldcf + n], val);
                    else        Cf[(size_t)m * ldcf + n] = val;
                }
                if (Cb) {
                    if (bmode == 0) {
                        Cb[(size_t)m * ldcb + n] = (__bf16)val;
                    } else { // 4: dual k | vT
                        __bf16 hv = (__bf16)val;
                        if (n < 1024) Cb[(size_t)m * ldcb + n] = hv;
                        else          Cb2[(size_t)(n - 1024) * ldcb2 + m] = hv;
                    }
                }
            }
        }
    }
}

// fp32 [rows][1024] -> bf16 [rows][3072] B-split (hi|hi|lo); idx over float4s
__device__ __forceinline__ void bsplit_seg(
    const float* __restrict__ src, __bf16* __restrict__ dst, int idx)
{
    const int row = idx >> 8;
    const int c4  = (idx & 255) * 4;
    float4 f = ((const float4*)src)[idx];
    __bf16* p = dst + (size_t)row * 3072 + c4;
    float fa[4] = {f.x, f.y, f.z, f.w};
#pragma unroll
    for (int e = 0; e < 4; e++) {
        __bf16 hi = (__bf16)fa[e];
        p[e] = hi; p[1024 + e] = hi; p[2048 + e] = (__bf16)(fa[e] - (float)hi);
    }
}

// ---------------------------------------------------------------------------
// Merged launch 2: Wf = Wo@Wc (split-K x8, 512 blocks) || qc GEMM (160 blocks)
// ---------------------------------------------------------------------------
__global__ __launch_bounds__(256) void gemm_qcwf(
    const __bf16* __restrict__ WcT2a, const __bf16* __restrict__ Wo_rm,
    float* __restrict__ Wf_acc,
    const __bf16* __restrict__ emb_bf, const __bf16* __restrict__ Wqc_t,
    __bf16* __restrict__ qc_bf)
{
    __shared__ __bf16 sA[2][8192];
    __shared__ __bf16 sB[2][8192];
    int b = blockIdx.x;
    if (b < 512) {
        gemm_core(&sA[0][0], &sB[0][0], WcT2a, 3072, Wo_rm, 3072, 3072,
                  Wf_acc, 1024, nullptr, 0, 0, nullptr, 0,
                  b & 7, (b >> 3) & 7, b >> 6, 8);
    } else {
        b -= 512;
        gemm_core(&sA[0][0], &sB[0][0], emb_bf, 1024, Wqc_t, 1024, 1024,
                  nullptr, 0, qc_bf, 1280, 0, nullptr, 0,
                  b % 10, b / 10, 0, 1);
    }
}

// ---------------------------------------------------------------------------
// Merged launch 3: k|vT GEMM (256 blocks) || Wf bsplit (1024 blocks)
// ---------------------------------------------------------------------------
__global__ __launch_bounds__(256) void gemm_kvbs(
    const __bf16* __restrict__ qc_bf, const __bf16* __restrict__ Wukv_t,
    __bf16* __restrict__ k_bf, __bf16* __restrict__ vT_bf,
    const float* __restrict__ Wf_acc, __bf16* __restrict__ BtWheels)
{
    __shared__ __bf16 sA[2][8192];
    __shared__ __bf16 sB[2][8192];
    int b = blockIdx.x;
    if (b < 256) {
        gemm_core(&sA[0][0], &sB[0][0], qc_bf + 1024, 1280, Wukv_t, 256, 256,
                  nullptr, 0, k_bf, 1024, 4, vT_bf, 2048,
                  b & 15, b >> 4, 0, 1);
    } else {
        b -= 256;
        bsplit_seg(Wf_acc, BtWheels, b * 256 + threadIdx.x);
    }
}

// ---------------------------------------------------------------------------
// Final GEMM: 512 threads = 8 waves, wave = 64x32 quadrant of 128x128 tile.
// C fp32 [M][2048] = A[M,3072] @ Bt[2048,3072]^T + bias. Grid (16,16).
// ---------------------------------------------------------------------------
__global__ __launch_bounds__(512) void gemm512(
    const __bf16* __restrict__ A, int lda,
    const __bf16* __restrict__ Bt, int ldb, int K,
    float* __restrict__ Cf, int ldcf, const float* __restrict__ bias)
{
    __shared__ __bf16 sA[2][8192];
    __shared__ __bf16 sB[2][8192];

    const int tid  = threadIdx.x;
    const int lane = tid & 63;
    const int w    = tid >> 6;        // 0..7
    const int quad = lane >> 4;
    const int c0   = lane & 15;
    const int m0 = blockIdx.y * 128;
    const int n0 = blockIdx.x * 128;

    // staging: 2 chunks A + 2 chunks B per thread (1024 chunks each tile)
    const int sc = tid & 7;
    const __bf16* a_src[2]; const __bf16* b_src[2];
    int dstoff[2];
#pragma unroll
    for (int t = 0; t < 2; t++) {
        const int row = t * 64 + (tid >> 3);       // 0..127
        const int c = sc ^ (row & 7);
        a_src[t] = A  + (size_t)(m0 + row) * lda + c * 8;
        b_src[t] = Bt + (size_t)(n0 + row) * ldb + c * 8;
        dstoff[t] = (t * 64 + w * 8) * 64;         // wave-uniform base
    }

    const int mw = (w & 1) * 64;
    const int nw = (w >> 1) * 32;
    int arow[4], brow[2];
#pragma unroll
    for (int i = 0; i < 4; i++) arow[i] = mw + i * 16 + c0;
#pragma unroll
    for (int j = 0; j < 2; j++) brow[j] = nw + j * 16 + c0;

    f32x4 acc[4][2];
#pragma unroll
    for (int i = 0; i < 4; i++)
#pragma unroll
        for (int j = 0; j < 2; j++) acc[i][j] = (f32x4){0.f, 0.f, 0.f, 0.f};

#pragma unroll
    for (int t = 0; t < 2; t++) {
        gld_lds16(&sA[0][dstoff[t]], a_src[t]); a_src[t] += 64;
        gld_lds16(&sB[0][dstoff[t]], b_src[t]); b_src[t] += 64;
    }

    const int nkt = K >> 6;
    for (int kt = 0; kt < nkt; kt++) {
        __syncthreads();
        const int cur = kt & 1;
        if (kt + 1 < nkt) {
#pragma unroll
            for (int t = 0; t < 2; t++) {
                gld_lds16(&sA[cur ^ 1][dstoff[t]], a_src[t]); a_src[t] += 64;
                gld_lds16(&sB[cur ^ 1][dstoff[t]], b_src[t]); b_src[t] += 64;
            }
        }
#pragma unroll
        for (int ks = 0; ks < 2; ks++) {
            const int cb = ks * 4 + quad;
            bf16x8 af[4], bf[2];
#pragma unroll
            for (int i = 0; i < 4; i++)
                af[i] = *(const bf16x8*)&sA[cur][arow[i] * 64 + ((cb ^ (arow[i] & 7)) << 3)];
#pragma unroll
            for (int j = 0; j < 2; j++)
                bf[j] = *(const bf16x8*)&sB[cur][brow[j] * 64 + ((cb ^ (brow[j] & 7)) << 3)];
#pragma unroll
            for (int i = 0; i < 4; i++)
#pragma unroll
                for (int j = 0; j < 2; j++)
                    acc[i][j] = __builtin_amdgcn_mfma_f32_16x16x32_bf16(af[i], bf[j], acc[i][j], 0, 0, 0);
        }
    }

    float bias_v[2];
#pragma unroll
    for (int j = 0; j < 2; j++) bias_v[j] = bias[n0 + nw + j * 16 + c0];
#pragma unroll
    for (int i = 0; i < 4; i++) {
#pragma unroll
        for (int reg = 0; reg < 4; reg++) {
            const int m = m0 + mw + i * 16 + quad * 4 + reg;
#pragma unroll
            for (int j = 0; j < 2; j++) {
                const int n = n0 + nw + j * 16 + c0;
                Cf[(size_t)m * ldcf + n] = acc[i][j][reg] + bias_v[j];
            }
        }
    }
}

// ---------------------------------------------------------------------------
// MFMA flash attention (R4 version — proven): LDS dbuf staging via
// global_load_lds, fixed-max softmax, one barrier per K-tile.
// qs bf16 [S,QPITCH] (q pre-scaled, cols 0-1023); kk bf16 [S,1024];
// vT bf16 [1024,S]. Output ctx2 bf16 [S,3072] hi|lo|hi.
// ---------------------------------------------------------------------------
#define PITCH 72
#define SOFT_M0 16.0f

__global__ __launch_bounds__(256) void attn_mfma_kernel(
    const __bf16* __restrict__ qs,
    const __bf16* __restrict__ kk,
    const __bf16* __restrict__ vT,
    __bf16* __restrict__ ctx2)
{
    __shared__ __bf16 Ks[2][64 * 64];
    __shared__ __bf16 Vt[2][64 * 64];
    __shared__ __bf16 Ps[4 * 16 * PITCH];

    const int h  = blockIdx.y;
    const int qb = blockIdx.x;
    const int tid  = threadIdx.x;
    const int lane = tid & 63;
    const int w    = tid >> 6;
    const int quad = lane >> 4;
    const int c0   = lane & 15;

    bf16x8 qfrag[2];
    {
        const __bf16* qrow = qs + (size_t)(qb * 64 + w * 16 + c0) * QPITCH + h * HDIM;
        qfrag[0] = *(const bf16x8*)(qrow + quad * 8);
        qfrag[1] = *(const bf16x8*)(qrow + 32 + quad * 8);
    }

    const int srow = lane >> 3;
    const int sc   = lane & 7;
    const __bf16* k_src[2]; const __bf16* v_src[2];
    int dstoff[2];
#pragma unroll
    for (int t = 0; t < 2; t++) {
        const int row = w * 16 + t * 8 + srow;
        const int c = sc ^ (row & 7);
        k_src[t] = kk + (size_t)row * DMODEL + h * HDIM + c * 8;
        v_src[t] = vT + (size_t)(h * HDIM + row) * S_LEN + c * 8;
        dstoff[t] = (w * 16 + t * 8) * 64;
    }

    f32x4 Ofrag[4];
#pragma unroll
    for (int nb = 0; nb < 4; nb++) Ofrag[nb] = (f32x4){0.f, 0.f, 0.f, 0.f};
    float l_r[4] = {0.f, 0.f, 0.f, 0.f};

    __bf16* Pw = Ps + w * (16 * PITCH);

#pragma unroll
    for (int t = 0; t < 2; t++) {
        gld_lds16(&Ks[0][dstoff[t]], k_src[t]); k_src[t] += (size_t)64 * DMODEL;
        gld_lds16(&Vt[0][dstoff[t]], v_src[t]); v_src[t] += 64;
    }

    for (int kt = 0; kt < S_LEN / 64; kt++) {
        __syncthreads();
        const int cur = kt & 1;
        if (kt < S_LEN / 64 - 1) {
#pragma unroll
            for (int t = 0; t < 2; t++) {
                gld_lds16(&Ks[cur ^ 1][dstoff[t]], k_src[t]); k_src[t] += (size_t)64 * DMODEL;
                gld_lds16(&Vt[cur ^ 1][dstoff[t]], v_src[t]); v_src[t] += 64;
            }
        }

        f32x4 sfrag[4];
#pragma unroll
        for (int nb = 0; nb < 4; nb++) {
            f32x4 acc = (f32x4){0.f, 0.f, 0.f, 0.f};
            const int n = nb * 16 + c0;
#pragma unroll
            for (int ks = 0; ks < 2; ks++) {
                const int cb = ks * 4 + quad;
                bf16x8 bfr = *(const bf16x8*)&Ks[cur][n * 64 + ((cb ^ (n & 7)) << 3)];
                acc = __builtin_amdgcn_mfma_f32_16x16x32_bf16(qfrag[ks], bfr, acc, 0, 0, 0);
            }
            sfrag[nb] = acc;
        }

#pragma unroll
        for (int reg = 0; reg < 4; reg++) {
            float p0 = __expf(sfrag[0][reg] - SOFT_M0);
            float p1 = __expf(sfrag[1][reg] - SOFT_M0);
            float p2 = __expf(sfrag[2][reg] - SOFT_M0);
            float p3 = __expf(sfrag[3][reg] - SOFT_M0);
            sfrag[0][reg] = p0; sfrag[1][reg] = p1;
            sfrag[2][reg] = p2; sfrag[3][reg] = p3;
            l_r[reg] += p0 + p1 + p2 + p3;
        }

#pragma unroll
        for (int reg = 0; reg < 4; reg++) {
            const int prow = quad * 4 + reg;
#pragma unroll
            for (int nb = 0; nb < 4; nb++)
                Pw[prow * PITCH + nb * 16 + c0] = (__bf16)sfrag[nb][reg];
        }
        __asm__ __volatile__("s_waitcnt lgkmcnt(0)" ::: "memory");

        bf16x8 pfrag[2];
#pragma unroll
        for (int ks = 0; ks < 2; ks++)
            pfrag[ks] = *(const bf16x8*)&Pw[c0 * PITCH + ks * 32 + quad * 8];

#pragma unroll
        for (int nb = 0; nb < 4; nb++) {
            f32x4 acc = Ofrag[nb];
            const int n = nb * 16 + c0;
#pragma unroll
            for (int ks = 0; ks < 2; ks++) {
                const int cb = ks * 4 + quad;
                bf16x8 vf = *(const bf16x8*)&Vt[cur][n * 64 + ((cb ^ (n & 7)) << 3)];
                acc = __builtin_amdgcn_mfma_f32_16x16x32_bf16(pfrag[ks], vf, acc, 0, 0, 0);
            }
            Ofrag[nb] = acc;
        }
    }

    float inv_l[4];
#pragma unroll
    for (int reg = 0; reg < 4; reg++) {
        float rsum = l_r[reg];
#pragma unroll
        for (int mask = 1; mask < 16; mask <<= 1)
            rsum += __shfl_xor(rsum, mask, 64);
        inv_l[reg] = 1.0f / rsum;
    }

#pragma unroll
    for (int reg = 0; reg < 4; reg++) {
        const int row = qb * 64 + w * 16 + quad * 4 + reg;
#pragma unroll
        for (int nb = 0; nb < 4; nb++) {
            const int col = h * HDIM + nb * 16 + c0;
            float val = Ofrag[nb][reg] * inv_l[reg];
            __bf16 hi = (__bf16)val;
            __bf16 lo = (__bf16)(val - (float)hi);
            __bf16* p = ctx2 + (size_t)row * 3072 + col;
            p[0] = hi; p[1024] = lo; p[2048] = hi;
        }
    }
}

// ---------------------------------------------------------------------------
// megaprep: weight transposes/converts + emb convert + Wf zero + bias.
// 7944 blocks, one launch.
// ---------------------------------------------------------------------------
__device__ __forceinline__ void xpose_seg(float (*tile)[33],
    const float* __restrict__ src, __bf16* __restrict__ dst,
    int R, int C, int dpitch, int split, float scale, int bx, int by, int nbase0)
{
    const int r0 = by * 32, c0 = bx * 32;
    const int tr = threadIdx.x >> 5, tc = threadIdx.x & 31;
#pragma unroll
    for (int i = 0; i < 4; i++)
        tile[tr + i * 8][tc] = src[(size_t)(r0 + tr + i * 8) * C + c0 + tc];
    __syncthreads();
#pragma unroll
    for (int i = 0; i < 4; i++) {
        const int n = nbase0 + c0 + tr + i * 8;
        const int kk = r0 + tc;
        const float v = tile[tc][tr + i * 8] * scale;
        __bf16 hi = (__bf16)v;
        __bf16* dp = dst + (size_t)n * dpitch + kk;
        dp[0] = hi;
        if (split == 1)      { dp[R] = hi; dp[2 * R] = (__bf16)(v - (float)hi); }
        else if (split == 2) { dp[R] = (__bf16)(v - (float)hi); dp[2 * R] = hi; }
    }
}

__global__ __launch_bounds__(256) void megaprep_kernel(
    const float* __restrict__ emb, const float* __restrict__ Wq,
    const float* __restrict__ Wdkv, const float* __restrict__ Wuk,
    const float* __restrict__ Wuv, const float* __restrict__ Wo,
    const float* __restrict__ wheelW, const float* __restrict__ wheelB,
    __bf16* __restrict__ Wqc_t, __bf16* __restrict__ Wukv_t,
    __bf16* __restrict__ Bt_full, __bf16* __restrict__ WcT2a,
    __bf16* __restrict__ Wo_rm, __bf16* __restrict__ emb_bf,
    float* __restrict__ Wf_acc, float* __restrict__ biasbuf)
{
    __shared__ float tile[32][33];
    int b = blockIdx.x;
    const int tid = threadIdx.x;

    if (b < 1024) { xpose_seg(tile, Wq, Wqc_t, 1024, 1024, 1024, 0, 0.125f, b & 31, b >> 5, 0); return; }
    b -= 1024;
    if (b < 256)  { xpose_seg(tile, Wdkv, Wqc_t + 1048576, 1024, 256, 1024, 0, 1.f, b & 7, b >> 3, 0); return; }
    b -= 256;
    if (b < 256)  { xpose_seg(tile, Wuk, Wukv_t, 256, 1024, 256, 0, 1.f, b & 31, b >> 5, 0); return; }
    b -= 256;
    if (b < 256)  { xpose_seg(tile, Wuv, Wukv_t + 262144, 256, 1024, 256, 0, 1.f, b & 31, b >> 5, 0); return; }
    b -= 256;
    if (b < 1024) { xpose_seg(tile, Wo, Bt_full, 1024, 1024, 3072, 1, 1.f, b & 31, b >> 5, 0); return; }
    b -= 1024;
    if (b < 1024) {
        const int z = b >> 8, rem = b & 255;
        xpose_seg(tile, wheelW + (size_t)z * 262144, WcT2a, 1024, 256, 3072, 2, 1.f,
                  rem & 7, rem >> 3, z * 256);
        return;
    }
    b -= 1024;
    if (b < 1024) { bsplit_seg(Wo, Wo_rm, b * 256 + tid); return; }
    b -= 1024;
    if (b < 2048) {
        const int i = b * 256 + tid;
        float4 f = ((const float4*)emb)[i];
        bf16x4 v;
        v[0] = (__bf16)f.x; v[1] = (__bf16)f.y; v[2] = (__bf16)f.z; v[3] = (__bf16)f.w;
        ((bf16x4*)emb_bf)[i] = v;
        return;
    }
    b -= 2048;
    if (b < 1024) {
        ((float4*)Wf_acc)[b * 256 + tid] = make_float4(0.f, 0.f, 0.f, 0.f);
        return;
    }
    b -= 1024;
    if (b < 8) {
        const int i = b * 256 + tid;
        biasbuf[i] = (i < 1024) ? 0.f : wheelB[i - 1024];
    }
}

// ---------------------------------------------------------------------------
// Launch
// ---------------------------------------------------------------------------
extern "C" void kernel_launch(void* const* d_in, const int* in_sizes, int n_in,
                              void* d_out, int out_size, void* d_ws, size_t ws_size,
                              hipStream_t stream) {
    const float* emb    = (const float*)d_in[0];
    const float* Wq     = (const float*)d_in[1];
    const float* Wdkv   = (const float*)d_in[2];
    const float* Wuk    = (const float*)d_in[3];
    const float* Wuv    = (const float*)d_in[4];
    const float* Wo     = (const float*)d_in[5];
    const float* wheelW = (const float*)d_in[6];
    const float* wheelB = (const float*)d_in[7];
    float* out = (float*)d_out;

    // workspace (bf16 element offsets); high-water 46.7 MB (same as R5).
    // Lifetimes: ctx2 aliases {WcT2a,Wo_rm} (dead after L2); k_bf aliases
    // emb_bf (dead after L2). Wf_acc has its OWN slot (live L1-L3, while
    // qc_bf is being written in L2 — must not alias).
    __bf16* ws = (__bf16*)d_ws;
    __bf16* Bt_full = ws;                        // [2048][3072]  L1w/L3w, L5r
    __bf16* Wqc_t   = ws + 6291456;              // [1280][1024]  L1w, L2r
    __bf16* Wukv_t  = ws + 7602176;              // [2048][256]   L1w, L3r
    float*  biasbuf = (float*)(ws + 8126464);    // fp32[2048]    L1w, L5r
    __bf16* WcT2a   = ws + 8130560;              // [1024][3072]  L1w, L2r
    __bf16* Wo_rm   = ws + 11276288;             // [1024][3072]  L1w, L2r
    __bf16* ctx2    = ws + 8130560;              // [2048][3072]  L4w, L5r (alias)
    float*  Wf_acc  = (float*)(ws + 14422016);   // fp32[1024][1024] L1w,L2w,L3r
    __bf16* qc_bf   = ws + 16519168;             // [2048][1280]  L2w, L3r, L4r
    __bf16* emb_bf  = ws + 19140608;             // [2048][1024]  L1w, L2r
    __bf16* k_bf    = ws + 19140608;             // [2048][1024]  L3w, L4r (alias)
    __bf16* vT_bf   = ws + 21237760;             // [1024][2048]  L3w, L4r

    // L1: all prep
    megaprep_kernel<<<7944, 256, 0, stream>>>(
        emb, Wq, Wdkv, Wuk, Wuv, Wo, wheelW, wheelB,
        Wqc_t, Wukv_t, Bt_full, WcT2a, Wo_rm, emb_bf, Wf_acc, biasbuf);

    // L2: Wf = Wo@Wc (split-K x8) || qc = emb@[Wq|Wdkv]
    gemm_qcwf<<<672, 256, 0, stream>>>(WcT2a, Wo_rm, Wf_acc, emb_bf, Wqc_t, qc_bf);

    // L3: k|vT = ckv@[Wuk|Wuv] || Wf bsplit into Bt_full rows 1024..
    gemm_kvbs<<<1280, 256, 0, stream>>>(qc_bf, Wukv_t, k_bf, vT_bf,
                                        Wf_acc, Bt_full + (size_t)1024 * 3072);

    // L4: attention -> ctx2 (hi|lo|hi)
    attn_mfma_kernel<<<dim3(S_LEN / 64, NHEADS), 256, 0, stream>>>(qc_bf, k_bf, vT_bf, ctx2);

    // L5: out = ctx @ [Wo|Wf]^T + bias (512-thread blocks, 2 waves/SIMD)
    gemm512<<<dim3(16, 16), 512, 0, stream>>>(ctx2, 3072, Bt_full, 3072, 3072,
                                              out, 2048, biasbuf);
}

// Round 7
// 221.219 us; speedup vs baseline: 1.4965x; 1.1263x over previous
//
#include <hip/hip_runtime.h>
#include <math.h>

#define S_LEN 2048
#define DMODEL 1024
#define NHEADS 16
#define HDIM 64
#define QPITCH 1280   // q|ckv merged activation pitch

typedef __bf16 bf16x8 __attribute__((ext_vector_type(8)));
typedef __bf16 bf16x4 __attribute__((ext_vector_type(4)));
typedef float  f32x4  __attribute__((ext_vector_type(4)));

// async global->LDS, 16B per lane. LDS dest = wave-uniform base + lane*16.
__device__ __forceinline__ void gld_lds16(void* lds, const void* g) {
    __builtin_amdgcn_global_load_lds(
        (__attribute__((address_space(1))) void*)(g),
        (__attribute__((address_space(3))) void*)(lds), 16, 0, 0);
}

// ---------------------------------------------------------------------------
// bf16 MFMA GEMM core (device fn), double-buffered one-barrier pipeline.
// C[M,N] = A[M,K-slice] @ Bt[N,K-slice]^T over k-tiles [kt0, kt0+nkt).
// 128x128 tile, 256 thr = 4 waves. Plain stores only (no atomics).
// bf16 modes: 0 plain [m][n]; 4 dual (n<1024 row-major, n>=1024 transposed
// into Cb2).
// ---------------------------------------------------------------------------
__device__ __forceinline__ void gemm_core(
    __bf16* sA, __bf16* sB,                       // each [2][128*64]
    const __bf16* __restrict__ A, int lda,
    const __bf16* __restrict__ Bt, int ldb,
    int kt0, int nkt,
    float* __restrict__ Cf, int ldcf,
    __bf16* __restrict__ Cb, int ldcb, int bmode,
    __bf16* __restrict__ Cb2, int ldcb2,
    int bx, int by)
{
    const int tid  = threadIdx.x;
    const int lane = tid & 63;
    const int w    = tid >> 6;
    const int quad = lane >> 4;
    const int c0   = lane & 15;
    const int m0 = by * 128;
    const int n0 = bx * 128;

    const int srow = lane >> 3;
    const int sc   = lane & 7;
    const __bf16* a_src[4]; const __bf16* b_src[4];
    int dstoff[4];
#pragma unroll
    for (int t = 0; t < 4; t++) {
        const int row = w * 32 + t * 8 + srow;
        const int c = sc ^ (row & 7);
        a_src[t] = A  + (size_t)(m0 + row) * lda + kt0 * 64 + c * 8;
        b_src[t] = Bt + (size_t)(n0 + row) * ldb + kt0 * 64 + c * 8;
        dstoff[t] = (w * 32 + t * 8) * 64;
    }

    const int mw = (w & 1) * 64;
    const int nw = (w >> 1) * 64;
    int arow[4], brow[4];
#pragma unroll
    for (int i = 0; i < 4; i++) {
        arow[i] = mw + i * 16 + c0;
        brow[i] = nw + i * 16 + c0;
    }

    f32x4 acc[4][4];
#pragma unroll
    for (int i = 0; i < 4; i++)
#pragma unroll
        for (int j = 0; j < 4; j++) acc[i][j] = (f32x4){0.f, 0.f, 0.f, 0.f};

#pragma unroll
    for (int t = 0; t < 4; t++) {
        gld_lds16(&sA[dstoff[t]], a_src[t]); a_src[t] += 64;
        gld_lds16(&sB[dstoff[t]], b_src[t]); b_src[t] += 64;
    }

    for (int kt = 0; kt < nkt; kt++) {
        __syncthreads();
        const int cur = kt & 1;
        if (kt + 1 < nkt) {
#pragma unroll
            for (int t = 0; t < 4; t++) {
                gld_lds16(&sA[(cur ^ 1) * 8192 + dstoff[t]], a_src[t]); a_src[t] += 64;
                gld_lds16(&sB[(cur ^ 1) * 8192 + dstoff[t]], b_src[t]); b_src[t] += 64;
            }
        }
#pragma unroll
        for (int ks = 0; ks < 2; ks++) {
            const int cb = ks * 4 + quad;
            bf16x8 af[4], bf[4];
#pragma unroll
            for (int i = 0; i < 4; i++)
                af[i] = *(const bf16x8*)&sA[cur * 8192 + arow[i] * 64 + ((cb ^ (arow[i] & 7)) << 3)];
#pragma unroll
            for (int j = 0; j < 4; j++)
                bf[j] = *(const bf16x8*)&sB[cur * 8192 + brow[j] * 64 + ((cb ^ (brow[j] & 7)) << 3)];
#pragma unroll
            for (int i = 0; i < 4; i++)
#pragma unroll
                for (int j = 0; j < 4; j++)
                    acc[i][j] = __builtin_amdgcn_mfma_f32_16x16x32_bf16(af[i], bf[j], acc[i][j], 0, 0, 0);
        }
    }

#pragma unroll
    for (int i = 0; i < 4; i++) {
#pragma unroll
        for (int reg = 0; reg < 4; reg++) {
            const int m = m0 + mw + i * 16 + quad * 4 + reg;
#pragma unroll
            for (int j = 0; j < 4; j++) {
                const int n = n0 + nw + j * 16 + c0;
                float val = acc[i][j][reg];
                if (Cf) Cf[(size_t)m * ldcf + n] = val;
                if (Cb) {
                    if (bmode == 0) {
                        Cb[(size_t)m * ldcb + n] = (__bf16)val;
                    } else { // 4: dual k | vT
                        __bf16 hv = (__bf16)val;
                        if (n < 1024) Cb[(size_t)m * ldcb + n] = hv;
                        else          Cb2[(size_t)(n - 1024) * ldcb2 + m] = hv;
                    }
                }
            }
        }
    }
}

// fp32 [rows][1024] -> bf16 [rows][3072] B-split (hi|hi|lo); idx over float4s
__device__ __forceinline__ void bsplit_seg(
    const float* __restrict__ src, __bf16* __restrict__ dst, int idx)
{
    const int row = idx >> 8;
    const int c4  = (idx & 255) * 4;
    float4 f = ((const float4*)src)[idx];
    __bf16* p = dst + (size_t)row * 3072 + c4;
    float fa[4] = {f.x, f.y, f.z, f.w};
#pragma unroll
    for (int e = 0; e < 4; e++) {
        __bf16 hi = (__bf16)fa[e];
        p[e] = hi; p[1024 + e] = hi; p[2048 + e] = (__bf16)(fa[e] - (float)hi);
    }
}

// sum of two fp32 sources -> B-split
__device__ __forceinline__ void bsplit2_seg(
    const float* __restrict__ s0, const float* __restrict__ s1,
    __bf16* __restrict__ dst, int idx)
{
    const int row = idx >> 8;
    const int c4  = (idx & 255) * 4;
    float4 f0 = ((const float4*)s0)[idx];
    float4 f1 = ((const float4*)s1)[idx];
    __bf16* p = dst + (size_t)row * 3072 + c4;
    float fa[4] = {f0.x + f1.x, f0.y + f1.y, f0.z + f1.z, f0.w + f1.w};
#pragma unroll
    for (int e = 0; e < 4; e++) {
        __bf16 hi = (__bf16)fa[e];
        p[e] = hi; p[1024 + e] = hi; p[2048 + e] = (__bf16)(fa[e] - (float)hi);
    }
}

// ---------------------------------------------------------------------------
// L2: Wf = Wo@Wc split-K x2 into Wf0/Wf1 (128 blocks, plain stores)
//     || qc GEMM (160 blocks)
// ---------------------------------------------------------------------------
__global__ __launch_bounds__(256) void gemm_qcwf(
    const __bf16* __restrict__ WcT2a, const __bf16* __restrict__ Wo_rm,
    float* __restrict__ Wf0, float* __restrict__ Wf1,
    const __bf16* __restrict__ emb_bf, const __bf16* __restrict__ Wqc_t,
    __bf16* __restrict__ qc_bf)
{
    __shared__ __bf16 sA[2][8192];
    __shared__ __bf16 sB[2][8192];
    int b = blockIdx.x;
    if (b < 128) {
        const int z = b >> 6, rem = b & 63;
        gemm_core(&sA[0][0], &sB[0][0], WcT2a, 3072, Wo_rm, 3072, z * 24, 24,
                  z ? Wf1 : Wf0, 1024, nullptr, 0, 0, nullptr, 0,
                  rem & 7, rem >> 3);
    } else {
        b -= 128;
        gemm_core(&sA[0][0], &sB[0][0], emb_bf, 1024, Wqc_t, 1024, 0, 16,
                  nullptr, 0, qc_bf, 1280, 0, nullptr, 0,
                  b % 10, b / 10);
    }
}

// ---------------------------------------------------------------------------
// L3: k|vT GEMM (256 blocks) || Wf0+Wf1 bsplit (1024 blocks)
// ---------------------------------------------------------------------------
__global__ __launch_bounds__(256) void gemm_kvbs(
    const __bf16* __restrict__ qc_bf, const __bf16* __restrict__ Wukv_t,
    __bf16* __restrict__ k_bf, __bf16* __restrict__ vT_bf,
    const float* __restrict__ Wf0, const float* __restrict__ Wf1,
    __bf16* __restrict__ BtWheels)
{
    __shared__ __bf16 sA[2][8192];
    __shared__ __bf16 sB[2][8192];
    int b = blockIdx.x;
    if (b < 256) {
        gemm_core(&sA[0][0], &sB[0][0], qc_bf + 1024, 1280, Wukv_t, 256, 0, 4,
                  nullptr, 0, k_bf, 1024, 4, vT_bf, 2048,
                  b & 15, b >> 4);
    } else {
        b -= 256;
        bsplit2_seg(Wf0, Wf1, BtWheels, b * 256 + threadIdx.x);
    }
}

// ---------------------------------------------------------------------------
// Final GEMM: 512 threads = 8 waves, wave = 64x32 quadrant of 128x128 tile.
// C fp32 [M][2048] = A[M,3072] @ Bt[2048,3072]^T + bias. Grid (16,16).
// ---------------------------------------------------------------------------
__global__ __launch_bounds__(512) void gemm512(
    const __bf16* __restrict__ A, int lda,
    const __bf16* __restrict__ Bt, int ldb, int K,
    float* __restrict__ Cf, int ldcf, const float* __restrict__ bias)
{
    __shared__ __bf16 sA[2][8192];
    __shared__ __bf16 sB[2][8192];

    const int tid  = threadIdx.x;
    const int lane = tid & 63;
    const int w    = tid >> 6;        // 0..7
    const int quad = lane >> 4;
    const int c0   = lane & 15;
    const int m0 = blockIdx.y * 128;
    const int n0 = blockIdx.x * 128;

    const int sc = tid & 7;
    const __bf16* a_src[2]; const __bf16* b_src[2];
    int dstoff[2];
#pragma unroll
    for (int t = 0; t < 2; t++) {
        const int row = t * 64 + (tid >> 3);       // 0..127
        const int c = sc ^ (row & 7);
        a_src[t] = A  + (size_t)(m0 + row) * lda + c * 8;
        b_src[t] = Bt + (size_t)(n0 + row) * ldb + c * 8;
        dstoff[t] = (t * 64 + w * 8) * 64;         // wave-uniform base
    }

    const int mw = (w & 1) * 64;
    const int nw = (w >> 1) * 32;
    int arow[4], brow[2];
#pragma unroll
    for (int i = 0; i < 4; i++) arow[i] = mw + i * 16 + c0;
#pragma unroll
    for (int j = 0; j < 2; j++) brow[j] = nw + j * 16 + c0;

    f32x4 acc[4][2];
#pragma unroll
    for (int i = 0; i < 4; i++)
#pragma unroll
        for (int j = 0; j < 2; j++) acc[i][j] = (f32x4){0.f, 0.f, 0.f, 0.f};

#pragma unroll
    for (int t = 0; t < 2; t++) {
        gld_lds16(&sA[0][dstoff[t]], a_src[t]); a_src[t] += 64;
        gld_lds16(&sB[0][dstoff[t]], b_src[t]); b_src[t] += 64;
    }

    const int nkt = K >> 6;
    for (int kt = 0; kt < nkt; kt++) {
        __syncthreads();
        const int cur = kt & 1;
        if (kt + 1 < nkt) {
#pragma unroll
            for (int t = 0; t < 2; t++) {
                gld_lds16(&sA[cur ^ 1][dstoff[t]], a_src[t]); a_src[t] += 64;
                gld_lds16(&sB[cur ^ 1][dstoff[t]], b_src[t]); b_src[t] += 64;
            }
        }
#pragma unroll
        for (int ks = 0; ks < 2; ks++) {
            const int cb = ks * 4 + quad;
            bf16x8 af[4], bf[2];
#pragma unroll
            for (int i = 0; i < 4; i++)
                af[i] = *(const bf16x8*)&sA[cur][arow[i] * 64 + ((cb ^ (arow[i] & 7)) << 3)];
#pragma unroll
            for (int j = 0; j < 2; j++)
                bf[j] = *(const bf16x8*)&sB[cur][brow[j] * 64 + ((cb ^ (brow[j] & 7)) << 3)];
#pragma unroll
            for (int i = 0; i < 4; i++)
#pragma unroll
                for (int j = 0; j < 2; j++)
                    acc[i][j] = __builtin_amdgcn_mfma_f32_16x16x32_bf16(af[i], bf[j], acc[i][j], 0, 0, 0);
        }
    }

    float bias_v[2];
#pragma unroll
    for (int j = 0; j < 2; j++) bias_v[j] = bias[n0 + nw + j * 16 + c0];
#pragma unroll
    for (int i = 0; i < 4; i++) {
#pragma unroll
        for (int reg = 0; reg < 4; reg++) {
            const int m = m0 + mw + i * 16 + quad * 4 + reg;
#pragma unroll
            for (int j = 0; j < 2; j++) {
                const int n = n0 + nw + j * 16 + c0;
                Cf[(size_t)m * ldcf + n] = acc[i][j][reg] + bias_v[j];
            }
        }
    }
}

// ---------------------------------------------------------------------------
// MFMA flash attention v2: 32 Q-rows/wave (2 m-tiles, K/V fragments shared
// across both), key-split x2 (fixed-max softmax => partials are additive),
// LDS dbuf staging, one barrier per K-tile. Writes UNNORMALIZED fp32 partial
// O and per-row l; combine kernel normalizes.
// ---------------------------------------------------------------------------
#define PITCH 72
#define SOFT_M0 16.0f

__global__ __launch_bounds__(256) void attn_mfma_kernel(
    const __bf16* __restrict__ qs,   // [S, QPITCH], q pre-scaled, cols 0-1023
    const __bf16* __restrict__ kk,   // [S, 1024]
    const __bf16* __restrict__ vT,   // [1024, S]
    float* __restrict__ Opart,       // [2][S][1024]
    float* __restrict__ lpart)       // [2][16][S]
{
    __shared__ __bf16 Ks[2][64 * 64];
    __shared__ __bf16 Vt[2][64 * 64];
    __shared__ __bf16 Ps[4 * 32 * PITCH];

    const int qb = blockIdx.x;       // 0..15 (128 Q-rows each)
    const int h  = blockIdx.y;       // 0..15
    const int kz = blockIdx.z;       // 0..1 (1024 keys each)
    const int tid  = threadIdx.x;
    const int lane = tid & 63;
    const int w    = tid >> 6;
    const int quad = lane >> 4;
    const int c0   = lane & 15;

    // Q fragments: wave owns rows qb*128 + w*32 .. +32 (2 m-tiles)
    bf16x8 qfrag[2][2];
#pragma unroll
    for (int m = 0; m < 2; m++) {
        const __bf16* qrow = qs + (size_t)(qb * 128 + w * 32 + m * 16 + c0) * QPITCH + h * HDIM;
        qfrag[m][0] = *(const bf16x8*)(qrow + quad * 8);
        qfrag[m][1] = *(const bf16x8*)(qrow + 32 + quad * 8);
    }

    // cooperative staging of 64-key tiles
    const int srow = lane >> 3;
    const int sc   = lane & 7;
    const __bf16* k_src[2]; const __bf16* v_src[2];
    int dstoff[2];
#pragma unroll
    for (int t = 0; t < 2; t++) {
        const int row = w * 16 + t * 8 + srow;
        const int c = sc ^ (row & 7);
        k_src[t] = kk + (size_t)(kz * 1024 + row) * DMODEL + h * HDIM + c * 8;
        v_src[t] = vT + (size_t)(h * HDIM + row) * S_LEN + kz * 1024 + c * 8;
        dstoff[t] = (w * 16 + t * 8) * 64;
    }

    f32x4 Ofrag[2][4];
#pragma unroll
    for (int m = 0; m < 2; m++)
#pragma unroll
        for (int nb = 0; nb < 4; nb++) Ofrag[m][nb] = (f32x4){0.f, 0.f, 0.f, 0.f};
    float l_r[2][4] = {{0.f, 0.f, 0.f, 0.f}, {0.f, 0.f, 0.f, 0.f}};

    __bf16* Pw = Ps + w * (32 * PITCH);

#pragma unroll
    for (int t = 0; t < 2; t++) {
        gld_lds16(&Ks[0][dstoff[t]], k_src[t]); k_src[t] += (size_t)64 * DMODEL;
        gld_lds16(&Vt[0][dstoff[t]], v_src[t]); v_src[t] += 64;
    }

    for (int kt = 0; kt < 16; kt++) {
        __syncthreads();
        const int cur = kt & 1;
        if (kt < 15) {
#pragma unroll
            for (int t = 0; t < 2; t++) {
                gld_lds16(&Ks[cur ^ 1][dstoff[t]], k_src[t]); k_src[t] += (size_t)64 * DMODEL;
                gld_lds16(&Vt[cur ^ 1][dstoff[t]], v_src[t]); v_src[t] += 64;
            }
        }

        // scores: K fragment read once, used by both m-tiles
        f32x4 sfrag[2][4];
#pragma unroll
        for (int m = 0; m < 2; m++)
#pragma unroll
            for (int nb = 0; nb < 4; nb++) sfrag[m][nb] = (f32x4){0.f, 0.f, 0.f, 0.f};
#pragma unroll
        for (int nb = 0; nb < 4; nb++) {
            const int n = nb * 16 + c0;
#pragma unroll
            for (int ks = 0; ks < 2; ks++) {
                const int cb = ks * 4 + quad;
                bf16x8 kfr = *(const bf16x8*)&Ks[cur][n * 64 + ((cb ^ (n & 7)) << 3)];
#pragma unroll
                for (int m = 0; m < 2; m++)
                    sfrag[m][nb] = __builtin_amdgcn_mfma_f32_16x16x32_bf16(qfrag[m][ks], kfr, sfrag[m][nb], 0, 0, 0);
            }
        }

        // P = exp(s - M0); per-lane partial row sums
#pragma unroll
        for (int m = 0; m < 2; m++)
#pragma unroll
            for (int reg = 0; reg < 4; reg++) {
                float p0 = __expf(sfrag[m][0][reg] - SOFT_M0);
                float p1 = __expf(sfrag[m][1][reg] - SOFT_M0);
                float p2 = __expf(sfrag[m][2][reg] - SOFT_M0);
                float p3 = __expf(sfrag[m][3][reg] - SOFT_M0);
                sfrag[m][0][reg] = p0; sfrag[m][1][reg] = p1;
                sfrag[m][2][reg] = p2; sfrag[m][3][reg] = p3;
                l_r[m][reg] += p0 + p1 + p2 + p3;
            }

        // P: C-layout -> wave-local LDS strip -> A-layout
#pragma unroll
        for (int m = 0; m < 2; m++)
#pragma unroll
            for (int reg = 0; reg < 4; reg++) {
                const int prow = m * 16 + quad * 4 + reg;
#pragma unroll
                for (int nb = 0; nb < 4; nb++)
                    Pw[prow * PITCH + nb * 16 + c0] = (__bf16)sfrag[m][nb][reg];
            }
        __asm__ __volatile__("s_waitcnt lgkmcnt(0)" ::: "memory");

        bf16x8 pfrag[2][2];
#pragma unroll
        for (int m = 0; m < 2; m++)
#pragma unroll
            for (int ks = 0; ks < 2; ks++)
                pfrag[m][ks] = *(const bf16x8*)&Pw[(m * 16 + c0) * PITCH + ks * 32 + quad * 8];

        // O += P @ V : V fragment read once, used by both m-tiles
#pragma unroll
        for (int nb = 0; nb < 4; nb++) {
            const int n = nb * 16 + c0;
#pragma unroll
            for (int ks = 0; ks < 2; ks++) {
                const int cb = ks * 4 + quad;
                bf16x8 vf = *(const bf16x8*)&Vt[cur][n * 64 + ((cb ^ (n & 7)) << 3)];
#pragma unroll
                for (int m = 0; m < 2; m++)
                    Ofrag[m][nb] = __builtin_amdgcn_mfma_f32_16x16x32_bf16(pfrag[m][ks], vf, Ofrag[m][nb], 0, 0, 0);
            }
        }
    }

    // write unnormalized partials + l
#pragma unroll
    for (int m = 0; m < 2; m++) {
#pragma unroll
        for (int reg = 0; reg < 4; reg++) {
            const int row = qb * 128 + w * 32 + m * 16 + quad * 4 + reg;
            float rsum = l_r[m][reg];
#pragma unroll
            for (int mask = 1; mask < 16; mask <<= 1)
                rsum += __shfl_xor(rsum, mask, 64);
            if (c0 == 0) lpart[(size_t)(kz * 16 + h) * 2048 + row] = rsum;
            float* op = Opart + ((size_t)kz * 2048 + row) * 1024 + h * HDIM;
#pragma unroll
            for (int nb = 0; nb < 4; nb++)
                op[nb * 16 + c0] = Ofrag[m][nb][reg];
        }
    }
}

// ---------------------------------------------------------------------------
// combine: O = (O0+O1)/(l0+l1) -> ctx2 hi|lo|hi. Grid 2048 x 256 threads.
// ---------------------------------------------------------------------------
__global__ __launch_bounds__(256) void attn_combine_kernel(
    const float* __restrict__ Opart, const float* __restrict__ lpart,
    __bf16* __restrict__ ctx2)
{
    const int i = blockIdx.x * 256 + threadIdx.x;   // over 2048*256 float4s
    const int row = i >> 8;
    const int c4  = (i & 255) * 4;
    const int h = c4 >> 6;
    const float l = lpart[(size_t)h * 2048 + row] + lpart[(size_t)(16 + h) * 2048 + row];
    const float inv = 1.0f / l;
    float4 o0 = ((const float4*)(Opart + (size_t)row * 1024))[c4 >> 2];
    float4 o1 = ((const float4*)(Opart + (size_t)(2048 + row) * 1024))[c4 >> 2];
    float v[4] = {(o0.x + o1.x) * inv, (o0.y + o1.y) * inv,
                  (o0.z + o1.z) * inv, (o0.w + o1.w) * inv};
    __bf16* p = ctx2 + (size_t)row * 3072 + c4;
#pragma unroll
    for (int e = 0; e < 4; e++) {
        __bf16 hi = (__bf16)v[e];
        p[e] = hi; p[1024 + e] = (__bf16)(v[e] - (float)hi); p[2048 + e] = hi;
    }
}

// ---------------------------------------------------------------------------
// megaprep: weight transposes/converts + emb convert + bias. 6920 blocks.
// ---------------------------------------------------------------------------
__device__ __forceinline__ void xpose_seg(float (*tile)[33],
    const float* __restrict__ src, __bf16* __restrict__ dst,
    int R, int C, int dpitch, int split, float scale, int bx, int by, int nbase0)
{
    const int r0 = by * 32, c0 = bx * 32;
    const int tr = threadIdx.x >> 5, tc = threadIdx.x & 31;
#pragma unroll
    for (int i = 0; i < 4; i++)
        tile[tr + i * 8][tc] = src[(size_t)(r0 + tr + i * 8) * C + c0 + tc];
    __syncthreads();
#pragma unroll
    for (int i = 0; i < 4; i++) {
        const int n = nbase0 + c0 + tr + i * 8;
        const int kk = r0 + tc;
        const float v = tile[tc][tr + i * 8] * scale;
        __bf16 hi = (__bf16)v;
        __bf16* dp = dst + (size_t)n * dpitch + kk;
        dp[0] = hi;
        if (split == 1)      { dp[R] = hi; dp[2 * R] = (__bf16)(v - (float)hi); }
        else if (split == 2) { dp[R] = (__bf16)(v - (float)hi); dp[2 * R] = hi; }
    }
}

__global__ __launch_bounds__(256) void megaprep_kernel(
    const float* __restrict__ emb, const float* __restrict__ Wq,
    const float* __restrict__ Wdkv, const float* __restrict__ Wuk,
    const float* __restrict__ Wuv, const float* __restrict__ Wo,
    const float* __restrict__ wheelW, const float* __restrict__ wheelB,
    __bf16* __restrict__ Wqc_t, __bf16* __restrict__ Wukv_t,
    __bf16* __restrict__ Bt_full, __bf16* __restrict__ WcT2a,
    __bf16* __restrict__ Wo_rm, __bf16* __restrict__ emb_bf,
    float* __restrict__ biasbuf)
{
    __shared__ float tile[32][33];
    int b = blockIdx.x;
    const int tid = threadIdx.x;

    if (b < 1024) { xpose_seg(tile, Wq, Wqc_t, 1024, 1024, 1024, 0, 0.125f, b & 31, b >> 5, 0); return; }
    b -= 1024;
    if (b < 256)  { xpose_seg(tile, Wdkv, Wqc_t + 1048576, 1024, 256, 1024, 0, 1.f, b & 7, b >> 3, 0); return; }
    b -= 256;
    if (b < 256)  { xpose_seg(tile, Wuk, Wukv_t, 256, 1024, 256, 0, 1.f, b & 31, b >> 5, 0); return; }
    b -= 256;
    if (b < 256)  { xpose_seg(tile, Wuv, Wukv_t + 262144, 256, 1024, 256, 0, 1.f, b & 31, b >> 5, 0); return; }
    b -= 256;
    if (b < 1024) { xpose_seg(tile, Wo, Bt_full, 1024, 1024, 3072, 1, 1.f, b & 31, b >> 5, 0); return; }
    b -= 1024;
    if (b < 1024) {
        const int z = b >> 8, rem = b & 255;
        xpose_seg(tile, wheelW + (size_t)z * 262144, WcT2a, 1024, 256, 3072, 2, 1.f,
                  rem & 7, rem >> 3, z * 256);
        return;
    }
    b -= 1024;
    if (b < 1024) { bsplit_seg(Wo, Wo_rm, b * 256 + tid); return; }
    b -= 1024;
    if (b < 2048) {
        const int i = b * 256 + tid;
        float4 f = ((const float4*)emb)[i];
        bf16x4 v;
        v[0] = (__bf16)f.x; v[1] = (__bf16)f.y; v[2] = (__bf16)f.z; v[3] = (__bf16)f.w;
        ((bf16x4*)emb_bf)[i] = v;
        return;
    }
    b -= 2048;
    if (b < 8) {
        const int i = b * 256 + tid;
        biasbuf[i] = (i < 1024) ? 0.f : wheelB[i - 1024];
    }
}

// ---------------------------------------------------------------------------
// Launch
// ---------------------------------------------------------------------------
extern "C" void kernel_launch(void* const* d_in, const int* in_sizes, int n_in,
                              void* d_out, int out_size, void* d_ws, size_t ws_size,
                              hipStream_t stream) {
    const float* emb    = (const float*)d_in[0];
    const float* Wq     = (const float*)d_in[1];
    const float* Wdkv   = (const float*)d_in[2];
    const float* Wuk    = (const float*)d_in[3];
    const float* Wuv    = (const float*)d_in[4];
    const float* Wo     = (const float*)d_in[5];
    const float* wheelW = (const float*)d_in[6];
    const float* wheelB = (const float*)d_in[7];
    float* out = (float*)d_out;

    // workspace (bf16 element offsets); high-water 50.9 MB.
    // Lifetimes: WcT2a/Wo_rm die after L2; Wf0/Wf1 die after L3;
    // Opart (L4w,L5r) aliases [WcT2a..Wf0]; lpart aliases Wf1;
    // ctx2 (L5w,L6r) aliases [qc_bf..vT_bf] (all die after L4);
    // k_bf aliases emb_bf (dies after L2).
    __bf16* ws = (__bf16*)d_ws;
    __bf16* Bt_full = ws;                        // [2048][3072]  L1w/L3w, L6r
    __bf16* Wqc_t   = ws + 6291456;              // [1280][1024]  L1w, L2r
    __bf16* Wukv_t  = ws + 7602176;              // [2048][256]   L1w, L3r
    float*  biasbuf = (float*)(ws + 8126464);    // fp32[2048]    L1w, L6r
    __bf16* WcT2a   = ws + 8130560;              // [1024][3072]  L1w, L2r
    __bf16* Wo_rm   = ws + 11276288;             // [1024][3072]  L1w, L2r
    float*  Opart   = (float*)(ws + 8130560);    // fp32[2][2048][1024] L4w, L5r
    float*  Wf0     = (float*)(ws + 14422016);   // fp32[1024][1024] L2w, L3r
    float*  Wf1     = (float*)(ws + 16519168);   // fp32[1024][1024] L2w, L3r
    float*  lpart   = (float*)(ws + 16519168);   // fp32[2][16][2048] L4w, L5r
    __bf16* qc_bf   = ws + 18616320;             // [2048][1280]  L2w, L3r, L4r
    __bf16* ctx2    = ws + 18616320;             // [2048][3072]  L5w, L6r (alias)
    __bf16* emb_bf  = ws + 21237760;             // [2048][1024]  L1w, L2r
    __bf16* k_bf    = ws + 21237760;             // [2048][1024]  L3w, L4r (alias)
    __bf16* vT_bf   = ws + 23334912;             // [1024][2048]  L3w, L4r

    // L1: all prep
    megaprep_kernel<<<6920, 256, 0, stream>>>(
        emb, Wq, Wdkv, Wuk, Wuv, Wo, wheelW, wheelB,
        Wqc_t, Wukv_t, Bt_full, WcT2a, Wo_rm, emb_bf, biasbuf);

    // L2: Wf = Wo@Wc (split-K x2, plain stores) || qc = emb@[Wq|Wdkv]
    gemm_qcwf<<<288, 256, 0, stream>>>(WcT2a, Wo_rm, Wf0, Wf1, emb_bf, Wqc_t, qc_bf);

    // L3: k|vT = ckv@[Wuk|Wuv] || (Wf0+Wf1) bsplit into Bt_full rows 1024..
    gemm_kvbs<<<1280, 256, 0, stream>>>(qc_bf, Wukv_t, k_bf, vT_bf,
                                        Wf0, Wf1, Bt_full + (size_t)1024 * 3072);

    // L4: attention (key-split x2) -> fp32 partials
    attn_mfma_kernel<<<dim3(16, 16, 2), 256, 0, stream>>>(qc_bf, k_bf, vT_bf, Opart, lpart);

    // L5: combine partials -> ctx2 (hi|lo|hi)
    attn_combine_kernel<<<2048, 256, 0, stream>>>(Opart, lpart, ctx2);

    // L6: out = ctx @ [Wo|Wf]^T + bias (512-thread blocks, 2 waves/SIMD)
    gemm512<<<dim3(16, 16), 512, 0, stream>>>(ctx2, 3072, Bt_full, 3072, 3072,
                                              out, 2048, biasbuf);
}

// Round 8
// 216.879 us; speedup vs baseline: 1.5264x; 1.0200x over previous
//
#include <hip/hip_runtime.h>
#include <math.h>

#define S_LEN 2048
#define DMODEL 1024
#define NHEADS 16
#define HDIM 64
#define QPITCH 1280   // q|ckv merged activation pitch

typedef __bf16 bf16x8 __attribute__((ext_vector_type(8)));
typedef __bf16 bf16x4 __attribute__((ext_vector_type(4)));
typedef float  f32x4  __attribute__((ext_vector_type(4)));

// async global->LDS, 16B per lane. LDS dest = wave-uniform base + lane*16.
__device__ __forceinline__ void gld_lds16(void* lds, const void* g) {
    __builtin_amdgcn_global_load_lds(
        (__attribute__((address_space(1))) void*)(g),
        (__attribute__((address_space(3))) void*)(lds), 16, 0, 0);
}

// ---------------------------------------------------------------------------
// bf16 MFMA GEMM core (device fn), double-buffered one-barrier pipeline.
// C[M,N] = A[M,K-slice] @ Bt[N,K-slice]^T over k-tiles [kt0, kt0+nkt).
// 128x128 tile, 256 thr = 4 waves (64x64 wave tile = 0.5 LDS reads/MFMA).
// Plain stores only. bf16 modes: 0 plain [m][n]; 4 dual (n<1024 row-major,
// n>=1024 transposed into Cb2).
// ---------------------------------------------------------------------------
__device__ __forceinline__ void gemm_core(
    __bf16* sA, __bf16* sB,                       // each [2][128*64]
    const __bf16* __restrict__ A, int lda,
    const __bf16* __restrict__ Bt, int ldb,
    int kt0, int nkt,
    float* __restrict__ Cf, int ldcf,
    __bf16* __restrict__ Cb, int ldcb, int bmode,
    __bf16* __restrict__ Cb2, int ldcb2,
    int bx, int by)
{
    const int tid  = threadIdx.x;
    const int lane = tid & 63;
    const int w    = tid >> 6;
    const int quad = lane >> 4;
    const int c0   = lane & 15;
    const int m0 = by * 128;
    const int n0 = bx * 128;

    const int srow = lane >> 3;
    const int sc   = lane & 7;
    const __bf16* a_src[4]; const __bf16* b_src[4];
    int dstoff[4];
#pragma unroll
    for (int t = 0; t < 4; t++) {
        const int row = w * 32 + t * 8 + srow;
        const int c = sc ^ (row & 7);
        a_src[t] = A  + (size_t)(m0 + row) * lda + kt0 * 64 + c * 8;
        b_src[t] = Bt + (size_t)(n0 + row) * ldb + kt0 * 64 + c * 8;
        dstoff[t] = (w * 32 + t * 8) * 64;
    }

    const int mw = (w & 1) * 64;
    const int nw = (w >> 1) * 64;
    int arow[4], brow[4];
#pragma unroll
    for (int i = 0; i < 4; i++) {
        arow[i] = mw + i * 16 + c0;
        brow[i] = nw + i * 16 + c0;
    }

    f32x4 acc[4][4];
#pragma unroll
    for (int i = 0; i < 4; i++)
#pragma unroll
        for (int j = 0; j < 4; j++) acc[i][j] = (f32x4){0.f, 0.f, 0.f, 0.f};

#pragma unroll
    for (int t = 0; t < 4; t++) {
        gld_lds16(&sA[dstoff[t]], a_src[t]); a_src[t] += 64;
        gld_lds16(&sB[dstoff[t]], b_src[t]); b_src[t] += 64;
    }

    for (int kt = 0; kt < nkt; kt++) {
        __syncthreads();
        const int cur = kt & 1;
        if (kt + 1 < nkt) {
#pragma unroll
            for (int t = 0; t < 4; t++) {
                gld_lds16(&sA[(cur ^ 1) * 8192 + dstoff[t]], a_src[t]); a_src[t] += 64;
                gld_lds16(&sB[(cur ^ 1) * 8192 + dstoff[t]], b_src[t]); b_src[t] += 64;
            }
        }
#pragma unroll
        for (int ks = 0; ks < 2; ks++) {
            const int cb = ks * 4 + quad;
            bf16x8 af[4], bf[4];
#pragma unroll
            for (int i = 0; i < 4; i++)
                af[i] = *(const bf16x8*)&sA[cur * 8192 + arow[i] * 64 + ((cb ^ (arow[i] & 7)) << 3)];
#pragma unroll
            for (int j = 0; j < 4; j++)
                bf[j] = *(const bf16x8*)&sB[cur * 8192 + brow[j] * 64 + ((cb ^ (brow[j] & 7)) << 3)];
#pragma unroll
            for (int i = 0; i < 4; i++)
#pragma unroll
                for (int j = 0; j < 4; j++)
                    acc[i][j] = __builtin_amdgcn_mfma_f32_16x16x32_bf16(af[i], bf[j], acc[i][j], 0, 0, 0);
        }
    }

#pragma unroll
    for (int i = 0; i < 4; i++) {
#pragma unroll
        for (int reg = 0; reg < 4; reg++) {
            const int m = m0 + mw + i * 16 + quad * 4 + reg;
#pragma unroll
            for (int j = 0; j < 4; j++) {
                const int n = n0 + nw + j * 16 + c0;
                float val = acc[i][j][reg];
                if (Cf) Cf[(size_t)m * ldcf + n] = val;
                if (Cb) {
                    if (bmode == 0) {
                        Cb[(size_t)m * ldcb + n] = (__bf16)val;
                    } else { // 4: dual k | vT
                        __bf16 hv = (__bf16)val;
                        if (n < 1024) Cb[(size_t)m * ldcb + n] = hv;
                        else          Cb2[(size_t)(n - 1024) * ldcb2 + m] = hv;
                    }
                }
            }
        }
    }
}

// fp32 [rows][1024] -> bf16 [rows][3072] B-split (hi|hi|lo); idx over float4s
__device__ __forceinline__ void bsplit_seg(
    const float* __restrict__ src, __bf16* __restrict__ dst, int idx)
{
    const int row = idx >> 8;
    const int c4  = (idx & 255) * 4;
    float4 f = ((const float4*)src)[idx];
    __bf16* p = dst + (size_t)row * 3072 + c4;
    float fa[4] = {f.x, f.y, f.z, f.w};
#pragma unroll
    for (int e = 0; e < 4; e++) {
        __bf16 hi = (__bf16)fa[e];
        p[e] = hi; p[1024 + e] = hi; p[2048 + e] = (__bf16)(fa[e] - (float)hi);
    }
}

// sum of two fp32 sources -> B-split
__device__ __forceinline__ void bsplit2_seg(
    const float* __restrict__ s0, const float* __restrict__ s1,
    __bf16* __restrict__ dst, int idx)
{
    const int row = idx >> 8;
    const int c4  = (idx & 255) * 4;
    float4 f0 = ((const float4*)s0)[idx];
    float4 f1 = ((const float4*)s1)[idx];
    __bf16* p = dst + (size_t)row * 3072 + c4;
    float fa[4] = {f0.x + f1.x, f0.y + f1.y, f0.z + f1.z, f0.w + f1.w};
#pragma unroll
    for (int e = 0; e < 4; e++) {
        __bf16 hi = (__bf16)fa[e];
        p[e] = hi; p[1024 + e] = hi; p[2048 + e] = (__bf16)(fa[e] - (float)hi);
    }
}

// ---------------------------------------------------------------------------
// L2: Wf = Wo@Wc split-K x2 into Wf0/Wf1 (128 blocks, plain stores)
//     || qc GEMM (160 blocks)
// ---------------------------------------------------------------------------
__global__ __launch_bounds__(256) void gemm_qcwf(
    const __bf16* __restrict__ WcT2a, const __bf16* __restrict__ Wo_rm,
    float* __restrict__ Wf0, float* __restrict__ Wf1,
    const __bf16* __restrict__ emb_bf, const __bf16* __restrict__ Wqc_t,
    __bf16* __restrict__ qc_bf)
{
    __shared__ __bf16 sA[2][8192];
    __shared__ __bf16 sB[2][8192];
    int b = blockIdx.x;
    if (b < 128) {
        const int z = b >> 6, rem = b & 63;
        gemm_core(&sA[0][0], &sB[0][0], WcT2a, 3072, Wo_rm, 3072, z * 24, 24,
                  z ? Wf1 : Wf0, 1024, nullptr, 0, 0, nullptr, 0,
                  rem & 7, rem >> 3);
    } else {
        b -= 128;
        gemm_core(&sA[0][0], &sB[0][0], emb_bf, 1024, Wqc_t, 1024, 0, 16,
                  nullptr, 0, qc_bf, 1280, 0, nullptr, 0,
                  b % 10, b / 10);
    }
}

// ---------------------------------------------------------------------------
// L3: k|vT GEMM (256 blocks) || Wf0+Wf1 bsplit (1024 blocks)
// ---------------------------------------------------------------------------
__global__ __launch_bounds__(256) void gemm_kvbs(
    const __bf16* __restrict__ qc_bf, const __bf16* __restrict__ Wukv_t,
    __bf16* __restrict__ k_bf, __bf16* __restrict__ vT_bf,
    const float* __restrict__ Wf0, const float* __restrict__ Wf1,
    __bf16* __restrict__ BtWheels)
{
    __shared__ __bf16 sA[2][8192];
    __shared__ __bf16 sB[2][8192];
    int b = blockIdx.x;
    if (b < 256) {
        gemm_core(&sA[0][0], &sB[0][0], qc_bf + 1024, 1280, Wukv_t, 256, 0, 4,
                  nullptr, 0, k_bf, 1024, 4, vT_bf, 2048,
                  b & 15, b >> 4);
    } else {
        b -= 256;
        bsplit2_seg(Wf0, Wf1, BtWheels, b * 256 + threadIdx.x);
    }
}

// ---------------------------------------------------------------------------
// L6: final GEMM split-K x2, 512 blocks (2 blocks/CU co-resident).
// z=0 -> out directly (no bias); z=1 -> P1. combine_out adds P1 + bias.
// ---------------------------------------------------------------------------
__global__ __launch_bounds__(256) void gemm_fin(
    const __bf16* __restrict__ A, const __bf16* __restrict__ Bt,
    float* __restrict__ C0, float* __restrict__ C1)
{
    __shared__ __bf16 sA[2][8192];
    __shared__ __bf16 sB[2][8192];
    const int b = blockIdx.x;
    const int z = b >> 8;
    const int rem = b & 255;
    gemm_core(&sA[0][0], &sB[0][0], A, 3072, Bt, 3072, z * 24, 24,
              z ? C1 : C0, 2048, nullptr, 0, 0, nullptr, 0,
              rem & 15, rem >> 4);
}

// L7: out += P1 + bias. 4096 blocks x 256 threads over 2048x2048 fp32.
__global__ __launch_bounds__(256) void combine_out(
    float* __restrict__ out, const float* __restrict__ P1,
    const float* __restrict__ bias)
{
    const int i = blockIdx.x * 256 + threadIdx.x;   // float4 index
    const int n4 = (i & 511) * 4;                   // col within row
    float4 a = ((const float4*)out)[i];
    float4 p = ((const float4*)P1)[i];
    const float* bp = bias + n4;
    float4 r = make_float4(a.x + p.x + bp[0], a.y + p.y + bp[1],
                           a.z + p.z + bp[2], a.w + p.w + bp[3]);
    ((float4*)out)[i] = r;
}

// ---------------------------------------------------------------------------
// MFMA flash attention v2: 32 Q-rows/wave (2 m-tiles, K/V fragments shared),
// key-split x2 (fixed-max softmax => additive partials), LDS dbuf staging.
// Writes UNNORMALIZED fp32 partial O and per-row l; combine normalizes.
// ---------------------------------------------------------------------------
#define PITCH 72
#define SOFT_M0 16.0f

__global__ __launch_bounds__(256) void attn_mfma_kernel(
    const __bf16* __restrict__ qs,   // [S, QPITCH], q pre-scaled, cols 0-1023
    const __bf16* __restrict__ kk,   // [S, 1024]
    const __bf16* __restrict__ vT,   // [1024, S]
    float* __restrict__ Opart,       // [2][S][1024]
    float* __restrict__ lpart)       // [2][16][S]
{
    __shared__ __bf16 Ks[2][64 * 64];
    __shared__ __bf16 Vt[2][64 * 64];
    __shared__ __bf16 Ps[4 * 32 * PITCH];

    const int qb = blockIdx.x;       // 0..15 (128 Q-rows each)
    const int h  = blockIdx.y;       // 0..15
    const int kz = blockIdx.z;       // 0..1 (1024 keys each)
    const int tid  = threadIdx.x;
    const int lane = tid & 63;
    const int w    = tid >> 6;
    const int quad = lane >> 4;
    const int c0   = lane & 15;

    bf16x8 qfrag[2][2];
#pragma unroll
    for (int m = 0; m < 2; m++) {
        const __bf16* qrow = qs + (size_t)(qb * 128 + w * 32 + m * 16 + c0) * QPITCH + h * HDIM;
        qfrag[m][0] = *(const bf16x8*)(qrow + quad * 8);
        qfrag[m][1] = *(const bf16x8*)(qrow + 32 + quad * 8);
    }

    const int srow = lane >> 3;
    const int sc   = lane & 7;
    const __bf16* k_src[2]; const __bf16* v_src[2];
    int dstoff[2];
#pragma unroll
    for (int t = 0; t < 2; t++) {
        const int row = w * 16 + t * 8 + srow;
        const int c = sc ^ (row & 7);
        k_src[t] = kk + (size_t)(kz * 1024 + row) * DMODEL + h * HDIM + c * 8;
        v_src[t] = vT + (size_t)(h * HDIM + row) * S_LEN + kz * 1024 + c * 8;
        dstoff[t] = (w * 16 + t * 8) * 64;
    }

    f32x4 Ofrag[2][4];
#pragma unroll
    for (int m = 0; m < 2; m++)
#pragma unroll
        for (int nb = 0; nb < 4; nb++) Ofrag[m][nb] = (f32x4){0.f, 0.f, 0.f, 0.f};
    float l_r[2][4] = {{0.f, 0.f, 0.f, 0.f}, {0.f, 0.f, 0.f, 0.f}};

    __bf16* Pw = Ps + w * (32 * PITCH);

#pragma unroll
    for (int t = 0; t < 2; t++) {
        gld_lds16(&Ks[0][dstoff[t]], k_src[t]); k_src[t] += (size_t)64 * DMODEL;
        gld_lds16(&Vt[0][dstoff[t]], v_src[t]); v_src[t] += 64;
    }

    for (int kt = 0; kt < 16; kt++) {
        __syncthreads();
        const int cur = kt & 1;
        if (kt < 15) {
#pragma unroll
            for (int t = 0; t < 2; t++) {
                gld_lds16(&Ks[cur ^ 1][dstoff[t]], k_src[t]); k_src[t] += (size_t)64 * DMODEL;
                gld_lds16(&Vt[cur ^ 1][dstoff[t]], v_src[t]); v_src[t] += 64;
            }
        }

        f32x4 sfrag[2][4];
#pragma unroll
        for (int m = 0; m < 2; m++)
#pragma unroll
            for (int nb = 0; nb < 4; nb++) sfrag[m][nb] = (f32x4){0.f, 0.f, 0.f, 0.f};
#pragma unroll
        for (int nb = 0; nb < 4; nb++) {
            const int n = nb * 16 + c0;
#pragma unroll
            for (int ks = 0; ks < 2; ks++) {
                const int cb = ks * 4 + quad;
                bf16x8 kfr = *(const bf16x8*)&Ks[cur][n * 64 + ((cb ^ (n & 7)) << 3)];
#pragma unroll
                for (int m = 0; m < 2; m++)
                    sfrag[m][nb] = __builtin_amdgcn_mfma_f32_16x16x32_bf16(qfrag[m][ks], kfr, sfrag[m][nb], 0, 0, 0);
            }
        }

#pragma unroll
        for (int m = 0; m < 2; m++)
#pragma unroll
            for (int reg = 0; reg < 4; reg++) {
                float p0 = __expf(sfrag[m][0][reg] - SOFT_M0);
                float p1 = __expf(sfrag[m][1][reg] - SOFT_M0);
                float p2 = __expf(sfrag[m][2][reg] - SOFT_M0);
                float p3 = __expf(sfrag[m][3][reg] - SOFT_M0);
                sfrag[m][0][reg] = p0; sfrag[m][1][reg] = p1;
                sfrag[m][2][reg] = p2; sfrag[m][3][reg] = p3;
                l_r[m][reg] += p0 + p1 + p2 + p3;
            }

#pragma unroll
        for (int m = 0; m < 2; m++)
#pragma unroll
            for (int reg = 0; reg < 4; reg++) {
                const int prow = m * 16 + quad * 4 + reg;
#pragma unroll
                for (int nb = 0; nb < 4; nb++)
                    Pw[prow * PITCH + nb * 16 + c0] = (__bf16)sfrag[m][nb][reg];
            }
        __asm__ __volatile__("s_waitcnt lgkmcnt(0)" ::: "memory");

        bf16x8 pfrag[2][2];
#pragma unroll
        for (int m = 0; m < 2; m++)
#pragma unroll
            for (int ks = 0; ks < 2; ks++)
                pfrag[m][ks] = *(const bf16x8*)&Pw[(m * 16 + c0) * PITCH + ks * 32 + quad * 8];

#pragma unroll
        for (int nb = 0; nb < 4; nb++) {
            const int n = nb * 16 + c0;
#pragma unroll
            for (int ks = 0; ks < 2; ks++) {
                const int cb = ks * 4 + quad;
                bf16x8 vf = *(const bf16x8*)&Vt[cur][n * 64 + ((cb ^ (n & 7)) << 3)];
#pragma unroll
                for (int m = 0; m < 2; m++)
                    Ofrag[m][nb] = __builtin_amdgcn_mfma_f32_16x16x32_bf16(pfrag[m][ks], vf, Ofrag[m][nb], 0, 0, 0);
            }
        }
    }

#pragma unroll
    for (int m = 0; m < 2; m++) {
#pragma unroll
        for (int reg = 0; reg < 4; reg++) {
            const int row = qb * 128 + w * 32 + m * 16 + quad * 4 + reg;
            float rsum = l_r[m][reg];
#pragma unroll
            for (int mask = 1; mask < 16; mask <<= 1)
                rsum += __shfl_xor(rsum, mask, 64);
            if (c0 == 0) lpart[(size_t)(kz * 16 + h) * 2048 + row] = rsum;
            float* op = Opart + ((size_t)kz * 2048 + row) * 1024 + h * HDIM;
#pragma unroll
            for (int nb = 0; nb < 4; nb++)
                op[nb * 16 + c0] = Ofrag[m][nb][reg];
        }
    }
}

// ---------------------------------------------------------------------------
// L5: combine attention partials: O = (O0+O1)/(l0+l1) -> ctx2 hi|lo|hi.
// ---------------------------------------------------------------------------
__global__ __launch_bounds__(256) void attn_combine_kernel(
    const float* __restrict__ Opart, const float* __restrict__ lpart,
    __bf16* __restrict__ ctx2)
{
    const int i = blockIdx.x * 256 + threadIdx.x;   // over 2048*256 float4s
    const int row = i >> 8;
    const int c4  = (i & 255) * 4;
    const int h = c4 >> 6;
    const float l = lpart[(size_t)h * 2048 + row] + lpart[(size_t)(16 + h) * 2048 + row];
    const float inv = 1.0f / l;
    float4 o0 = ((const float4*)(Opart + (size_t)row * 1024))[c4 >> 2];
    float4 o1 = ((const float4*)(Opart + (size_t)(2048 + row) * 1024))[c4 >> 2];
    float v[4] = {(o0.x + o1.x) * inv, (o0.y + o1.y) * inv,
                  (o0.z + o1.z) * inv, (o0.w + o1.w) * inv};
    __bf16* p = ctx2 + (size_t)row * 3072 + c4;
#pragma unroll
    for (int e = 0; e < 4; e++) {
        __bf16 hi = (__bf16)v[e];
        p[e] = hi; p[1024 + e] = (__bf16)(v[e] - (float)hi); p[2048 + e] = hi;
    }
}

// ---------------------------------------------------------------------------
// megaprep: weight transposes/converts + emb convert + bias. 6920 blocks.
// ---------------------------------------------------------------------------
__device__ __forceinline__ void xpose_seg(float (*tile)[33],
    const float* __restrict__ src, __bf16* __restrict__ dst,
    int R, int C, int dpitch, int split, float scale, int bx, int by, int nbase0)
{
    const int r0 = by * 32, c0 = bx * 32;
    const int tr = threadIdx.x >> 5, tc = threadIdx.x & 31;
#pragma unroll
    for (int i = 0; i < 4; i++)
        tile[tr + i * 8][tc] = src[(size_t)(r0 + tr + i * 8) * C + c0 + tc];
    __syncthreads();
#pragma unroll
    for (int i = 0; i < 4; i++) {
        const int n = nbase0 + c0 + tr + i * 8;
        const int kk = r0 + tc;
        const float v = tile[tc][tr + i * 8] * scale;
        __bf16 hi = (__bf16)v;
        __bf16* dp = dst + (size_t)n * dpitch + kk;
        dp[0] = hi;
        if (split == 1)      { dp[R] = hi; dp[2 * R] = (__bf16)(v - (float)hi); }
        else if (split == 2) { dp[R] = (__bf16)(v - (float)hi); dp[2 * R] = hi; }
    }
}

__global__ __launch_bounds__(256) void megaprep_kernel(
    const float* __restrict__ emb, const float* __restrict__ Wq,
    const float* __restrict__ Wdkv, const float* __restrict__ Wuk,
    const float* __restrict__ Wuv, const float* __restrict__ Wo,
    const float* __restrict__ wheelW, const float* __restrict__ wheelB,
    __bf16* __restrict__ Wqc_t, __bf16* __restrict__ Wukv_t,
    __bf16* __restrict__ Bt_full, __bf16* __restrict__ WcT2a,
    __bf16* __restrict__ Wo_rm, __bf16* __restrict__ emb_bf,
    float* __restrict__ biasbuf)
{
    __shared__ float tile[32][33];
    int b = blockIdx.x;
    const int tid = threadIdx.x;

    if (b < 1024) { xpose_seg(tile, Wq, Wqc_t, 1024, 1024, 1024, 0, 0.125f, b & 31, b >> 5, 0); return; }
    b -= 1024;
    if (b < 256)  { xpose_seg(tile, Wdkv, Wqc_t + 1048576, 1024, 256, 1024, 0, 1.f, b & 7, b >> 3, 0); return; }
    b -= 256;
    if (b < 256)  { xpose_seg(tile, Wuk, Wukv_t, 256, 1024, 256, 0, 1.f, b & 31, b >> 5, 0); return; }
    b -= 256;
    if (b < 256)  { xpose_seg(tile, Wuv, Wukv_t + 262144, 256, 1024, 256, 0, 1.f, b & 31, b >> 5, 0); return; }
    b -= 256;
    if (b < 1024) { xpose_seg(tile, Wo, Bt_full, 1024, 1024, 3072, 1, 1.f, b & 31, b >> 5, 0); return; }
    b -= 1024;
    if (b < 1024) {
        const int z = b >> 8, rem = b & 255;
        xpose_seg(tile, wheelW + (size_t)z * 262144, WcT2a, 1024, 256, 3072, 2, 1.f,
                  rem & 7, rem >> 3, z * 256);
        return;
    }
    b -= 1024;
    if (b < 1024) { bsplit_seg(Wo, Wo_rm, b * 256 + tid); return; }
    b -= 1024;
    if (b < 2048) {
        const int i = b * 256 + tid;
        float4 f = ((const float4*)emb)[i];
        bf16x4 v;
        v[0] = (__bf16)f.x; v[1] = (__bf16)f.y; v[2] = (__bf16)f.z; v[3] = (__bf16)f.w;
        ((bf16x4*)emb_bf)[i] = v;
        return;
    }
    b -= 2048;
    if (b < 8) {
        const int i = b * 256 + tid;
        biasbuf[i] = (i < 1024) ? 0.f : wheelB[i - 1024];
    }
}

// ---------------------------------------------------------------------------
// Launch
// ---------------------------------------------------------------------------
extern "C" void kernel_launch(void* const* d_in, const int* in_sizes, int n_in,
                              void* d_out, int out_size, void* d_ws, size_t ws_size,
                              hipStream_t stream) {
    const float* emb    = (const float*)d_in[0];
    const float* Wq     = (const float*)d_in[1];
    const float* Wdkv   = (const float*)d_in[2];
    const float* Wuk    = (const float*)d_in[3];
    const float* Wuv    = (const float*)d_in[4];
    const float* Wo     = (const float*)d_in[5];
    const float* wheelW = (const float*)d_in[6];
    const float* wheelB = (const float*)d_in[7];
    float* out = (float*)d_out;

    // workspace (bf16 element offsets); high-water 50.9 MB (same as R7).
    // Lifetimes: WcT2a/Wo_rm die after L2; Wf0/Wf1 die after L3;
    // Opart (L4w,L5r) aliases [WcT2a..Wf0]; lpart aliases Wf1;
    // ctx2 (L5w,L6r) aliases [qc_bf..vT_bf]; k_bf aliases emb_bf;
    // P1 (L6w,L7r) aliases Opart region (dead after L5).
    __bf16* ws = (__bf16*)d_ws;
    __bf16* Bt_full = ws;                        // [2048][3072]  L1w/L3w, L6r
    __bf16* Wqc_t   = ws + 6291456;              // [1280][1024]  L1w, L2r
    __bf16* Wukv_t  = ws + 7602176;              // [2048][256]   L1w, L3r
    float*  biasbuf = (float*)(ws + 8126464);    // fp32[2048]    L1w, L7r
    __bf16* WcT2a   = ws + 8130560;              // [1024][3072]  L1w, L2r
    __bf16* Wo_rm   = ws + 11276288;             // [1024][3072]  L1w, L2r
    float*  Opart   = (float*)(ws + 8130560);    // fp32[2][2048][1024] L4w, L5r
    float*  P1      = (float*)(ws + 8130560);    // fp32[2048][2048] L6w, L7r (alias)
    float*  Wf0     = (float*)(ws + 14422016);   // fp32[1024][1024] L2w, L3r
    float*  Wf1     = (float*)(ws + 16519168);   // fp32[1024][1024] L2w, L3r
    float*  lpart   = (float*)(ws + 16519168);   // fp32[2][16][2048] L4w, L5r
    __bf16* qc_bf   = ws + 18616320;             // [2048][1280]  L2w, L3r, L4r
    __bf16* ctx2    = ws + 18616320;             // [2048][3072]  L5w, L6r (alias)
    __bf16* emb_bf  = ws + 21237760;             // [2048][1024]  L1w, L2r
    __bf16* k_bf    = ws + 21237760;             // [2048][1024]  L3w, L4r (alias)
    __bf16* vT_bf   = ws + 23334912;             // [1024][2048]  L3w, L4r

    // L1: all prep
    megaprep_kernel<<<6920, 256, 0, stream>>>(
        emb, Wq, Wdkv, Wuk, Wuv, Wo, wheelW, wheelB,
        Wqc_t, Wukv_t, Bt_full, WcT2a, Wo_rm, emb_bf, biasbuf);

    // L2: Wf = Wo@Wc (split-K x2, plain stores) || qc = emb@[Wq|Wdkv]
    gemm_qcwf<<<288, 256, 0, stream>>>(WcT2a, Wo_rm, Wf0, Wf1, emb_bf, Wqc_t, qc_bf);

    // L3: k|vT = ckv@[Wuk|Wuv] || (Wf0+Wf1) bsplit into Bt_full rows 1024..
    gemm_kvbs<<<1280, 256, 0, stream>>>(qc_bf, Wukv_t, k_bf, vT_bf,
                                        Wf0, Wf1, Bt_full + (size_t)1024 * 3072);

    // L4: attention (key-split x2) -> fp32 partials
    attn_mfma_kernel<<<dim3(16, 16, 2), 256, 0, stream>>>(qc_bf, k_bf, vT_bf, Opart, lpart);

    // L5: combine partials -> ctx2 (hi|lo|hi)
    attn_combine_kernel<<<2048, 256, 0, stream>>>(Opart, lpart, ctx2);

    // L6: out = ctx @ [Wo|Wf]^T, split-K x2 (512 blocks, 2/CU co-resident)
    gemm_fin<<<512, 256, 0, stream>>>(ctx2, Bt_full, out, P1);

    // L7: out += P1 + bias
    combine_out<<<4096, 256, 0, stream>>>(out, P1, biasbuf);
}